// Round 1
// baseline (1103.555 us; speedup 1.0000x reference)
//
#include <hip/hip_runtime.h>
#include <math.h>

// Problem constants
constexpr int kD  = 1024;   // model dim
constexpr int kB  = 512;    // batch
constexpr int kN  = 512;    // states per batch
constexpr int kDH = 512;    // head dim (H=2)

// ---------------------------------------------------------------------------
// Generic 64x64 f32 GEMM, 4x4 per thread, BK=16.
// TRANSB=true : C[m,n] = sum_k A[m,k] * Bm[n,k]   (B row-major [N x K])
// TRANSB=false: C[m,n] = sum_k A[m,k] * Bm[k,n]   (B row-major [K x N])
// blockIdx.z batching via explicit strides. M,N multiples of 64; K mult of 16.
// ---------------------------------------------------------------------------
template<bool TRANSB>
__global__ __launch_bounds__(256)
void gemm64(int M, int Nn, int K,
            const float* __restrict__ A, int lda, long sAz,
            const float* __restrict__ Bmat, int ldb, long sBz,
            float* __restrict__ C, int ldc, long sCz,
            const float* __restrict__ bias, long sbz)
{
    (void)M; (void)Nn;
    A    += (long)blockIdx.z * sAz;
    Bmat += (long)blockIdx.z * sBz;
    C    += (long)blockIdx.z * sCz;

    __shared__ float As[16][64];
    __shared__ float Bs[16][64];

    const int bm = blockIdx.y * 64;
    const int bn = blockIdx.x * 64;
    const int tid = threadIdx.x;
    const int ty = tid >> 4, tx = tid & 15;      // compute mapping
    const int ar = tid >> 2, ak = (tid & 3) * 4; // A/B-T staging mapping
    const int nk = tid >> 4, nn = (tid & 15) * 4;// B-N staging mapping

    float acc[4][4] = {};

    for (int k0 = 0; k0 < K; k0 += 16) {
        float4 av = *(const float4*)(A + (long)(bm + ar) * lda + (k0 + ak));
        float4 bv;
        if (TRANSB)
            bv = *(const float4*)(Bmat + (long)(bn + ar) * ldb + (k0 + ak));
        else
            bv = *(const float4*)(Bmat + (long)(k0 + nk) * ldb + (bn + nn));

        __syncthreads();   // previous tile compute done
        As[ak + 0][ar] = av.x; As[ak + 1][ar] = av.y;
        As[ak + 2][ar] = av.z; As[ak + 3][ar] = av.w;
        if (TRANSB) {
            Bs[ak + 0][ar] = bv.x; Bs[ak + 1][ar] = bv.y;
            Bs[ak + 2][ar] = bv.z; Bs[ak + 3][ar] = bv.w;
        } else {
            *(float4*)&Bs[nk][nn] = bv;
        }
        __syncthreads();

#pragma unroll
        for (int kk = 0; kk < 16; ++kk) {
            float4 a4 = *(const float4*)&As[kk][ty * 4];
            float4 b4 = *(const float4*)&Bs[kk][tx * 4];
            float ai[4] = {a4.x, a4.y, a4.z, a4.w};
            float bj[4] = {b4.x, b4.y, b4.z, b4.w};
#pragma unroll
            for (int i = 0; i < 4; ++i)
#pragma unroll
                for (int j = 0; j < 4; ++j)
                    acc[i][j] += ai[i] * bj[j];
        }
    }

    float4 bb = make_float4(0.f, 0.f, 0.f, 0.f);
    if (bias) {
        const float* bp = bias + (long)blockIdx.z * sbz;
        bb = *(const float4*)(bp + bn + tx * 4);
    }
#pragma unroll
    for (int i = 0; i < 4; ++i) {
        float4 o;
        o.x = acc[i][0] + bb.x; o.y = acc[i][1] + bb.y;
        o.z = acc[i][2] + bb.z; o.w = acc[i][3] + bb.w;
        *(float4*)(C + (long)(bm + ty * 4 + i) * ldc + bn + tx * 4) = o;
    }
}

// ---------------------------------------------------------------------------
// sconst[b][h] = q[b, h*512 : h*512+512] . bk[h*512 : ...]
// ---------------------------------------------------------------------------
__global__ __launch_bounds__(128)
void sconst_kernel(const float* __restrict__ q, const float* __restrict__ bk,
                   float* __restrict__ sconst)
{
    const int b = blockIdx.x;
    const int tid = threadIdx.x;
    const int h = tid >> 6, lane = tid & 63;
    float acc = 0.f;
#pragma unroll
    for (int i = 0; i < 8; ++i) {
        int j = lane + i * 64;
        acc += q[(long)b * kD + h * kDH + j] * bk[h * kDH + j];
    }
#pragma unroll
    for (int m = 32; m >= 1; m >>= 1) acc += __shfl_xor(acc, m);
    if (lane == 0) sconst[b * 2 + h] = acc;
}

// ---------------------------------------------------------------------------
// Fused attention: one block per b. Computes
//   s[b][h][:] = sum_n softmax_n( (qt_h . x_n + qbk_h)/sqrt(DH) ) * x_n
// Single streaming pass over all_states[b] with online softmax.
// T=16-row tiles staged in LDS (64 KB); 512 threads (8 waves).
// ---------------------------------------------------------------------------
constexpr int kT = 16;
__global__ __launch_bounds__(512)
void attn_fused(const float* __restrict__ xall,   // [B][N][D]
                const float* __restrict__ qt,     // [B][2][D]
                const float* __restrict__ sconst, // [B][2]
                float* __restrict__ sout)         // [B][2][D]
{
    __shared__ float Xs[kT][kD];   // 64 KB
    __shared__ float sc[2][kT];
    __shared__ float pp[2][kT];
    __shared__ float ml[2][2];     // running max, running denom
    __shared__ float rs[2];        // per-tile rescale

    const int b = blockIdx.x;
    const int tid = threadIdx.x;
    const int wave = tid >> 6, lane = tid & 63;
    const float scale = 0.044194173824159216f;  // 1/sqrt(512)

    // q-tilde fragments: qt0/qt1[j] pair with x element d = lane + 64*j
    float qt0[16], qt1[16];
    const float* qb = qt + (long)b * 2 * kD;
#pragma unroll
    for (int j = 0; j < 16; ++j) {
        qt0[j] = qb[lane + 64 * j];
        qt1[j] = qb[kD + lane + 64 * j];
    }
    const float qbk0 = sconst[b * 2 + 0];
    const float qbk1 = sconst[b * 2 + 1];

    // s accumulator: thread owns 4 contiguous d of one head
    const int h  = tid >> 8;
    const int d0 = (tid & 255) * 4;
    float s0 = 0.f, s1 = 0.f, s2 = 0.f, s3 = 0.f;

    if (tid == 0) {
        ml[0][0] = -1e30f; ml[0][1] = 0.f;
        ml[1][0] = -1e30f; ml[1][1] = 0.f;
    }
    __syncthreads();

    const float4* xb = (const float4*)(xall + (long)b * kN * kD);
    float4* dst = (float4*)&Xs[0][0];

    for (int t = 0; t < kN / kT; ++t) {
        // ---- stage tile: global -> regs -> (barrier) -> LDS
        const float4* src = xb + (long)t * (kT * kD / 4);
        float4 tmp[8];
#pragma unroll
        for (int i = 0; i < 8; ++i) tmp[i] = src[tid + i * 512];
        __syncthreads();           // prior phase-B reads of Xs complete
#pragma unroll
        for (int i = 0; i < 8; ++i) dst[tid + i * 512] = tmp[i];
        __syncthreads();

        // ---- phase A: scores (wave handles 2 rows)
#pragma unroll
        for (int rr = 0; rr < 2; ++rr) {
            const int row = wave * 2 + rr;
            float a0 = 0.f, a1 = 0.f;
#pragma unroll
            for (int j = 0; j < 16; ++j) {
                float xv = Xs[row][lane + 64 * j];
                a0 += xv * qt0[j];
                a1 += xv * qt1[j];
            }
#pragma unroll
            for (int m = 32; m >= 1; m >>= 1) {
                a0 += __shfl_xor(a0, m);
                a1 += __shfl_xor(a1, m);
            }
            if (lane == 0) {
                sc[0][row] = (a0 + qbk0) * scale;
                sc[1][row] = (a1 + qbk1) * scale;
            }
        }
        __syncthreads();

        // ---- online-softmax stats: wave w (=head) lanes 0..15
        if (wave < 2 && lane < kT) {
            float v = sc[wave][lane];
            float mx = v;
#pragma unroll
            for (int m = 8; m >= 1; m >>= 1) mx = fmaxf(mx, __shfl_xor(mx, m));
            float mold = ml[wave][0], lold = ml[wave][1];
            float mnew = fmaxf(mold, mx);
            float p = __expf(v - mnew);
            pp[wave][lane] = p;
            float psum = p;
#pragma unroll
            for (int m = 8; m >= 1; m >>= 1) psum += __shfl_xor(psum, m);
            if (lane == 0) {
                float r = __expf(mold - mnew);
                ml[wave][0] = mnew;
                ml[wave][1] = lold * r + psum;
                rs[wave] = r;
            }
        }
        __syncthreads();

        // ---- phase B: s = s*r + sum_n p_n * x_n
        {
            float r = rs[h];
            s0 *= r; s1 *= r; s2 *= r; s3 *= r;
#pragma unroll
            for (int n = 0; n < kT; ++n) {
                float p = pp[h][n];
                float4 xv = *(const float4*)&Xs[n][d0];
                s0 += p * xv.x; s1 += p * xv.y;
                s2 += p * xv.z; s3 += p * xv.w;
            }
        }
    }

    const float inv = 1.0f / ml[h][1];
    float4 o = make_float4(s0 * inv, s1 * inv, s2 * inv, s3 * inv);
    *(float4*)(sout + (long)b * 2 * kD + h * kD + d0) = o;
}

// ---------------------------------------------------------------------------
// Gates GEMM: gates[b,n] = ctx.Wih[n,:1024] + ext.Wih[n,1024:2048]
//                        + h.Whh[n,:] + b_ih[n] + b_hh[n]
// Tile 64x128, BK=16, 256 threads, 4x8 per thread.
// ---------------------------------------------------------------------------
__global__ __launch_bounds__(256)
void gates_gemm(const float* __restrict__ ctxv,
                const float* __restrict__ ext,
                const float* __restrict__ hmat,
                const float* __restrict__ w_ih,   // [4096 x 2048]
                const float* __restrict__ w_hh,   // [4096 x 1024]
                const float* __restrict__ b_ih,
                const float* __restrict__ b_hh,
                float* __restrict__ gates)        // [512 x 4096]
{
    __shared__ float As[16][64];
    __shared__ float Bs[16][128];

    const int bm = blockIdx.y * 64;
    const int bn = blockIdx.x * 128;
    const int tid = threadIdx.x;
    const int ty = tid >> 4, tx = tid & 15;        // rows ty*4, cols tx*8
    const int ar = tid >> 2, ak = (tid & 3) * 4;   // A staging
    const int brn = tid >> 1, bk8 = (tid & 1) * 8; // B staging

    float acc[4][8] = {};

    for (int k0 = 0; k0 < 3072; k0 += 16) {
        // A source: [context | external | h], 1024 each (tiles never straddle)
        const int krel = k0 + ak;
        const float* Asrc = (krel < 1024) ? ctxv : (krel < 2048 ? ext : hmat);
        float4 av = *(const float4*)(Asrc + (long)(bm + ar) * kD + (krel & 1023));

        // B source: w_ih rows for k<2048, w_hh rows after
        const int kb = k0 + bk8;
        float4 bv0, bv1;
        if (kb < 2048) {
            const float* Bp = w_ih + (long)(bn + brn) * 2048 + kb;
            bv0 = *(const float4*)(Bp);
            bv1 = *(const float4*)(Bp + 4);
        } else {
            const float* Bp = w_hh + (long)(bn + brn) * 1024 + (kb - 2048);
            bv0 = *(const float4*)(Bp);
            bv1 = *(const float4*)(Bp + 4);
        }

        __syncthreads();
        As[ak + 0][ar] = av.x; As[ak + 1][ar] = av.y;
        As[ak + 2][ar] = av.z; As[ak + 3][ar] = av.w;
        Bs[bk8 + 0][brn] = bv0.x; Bs[bk8 + 1][brn] = bv0.y;
        Bs[bk8 + 2][brn] = bv0.z; Bs[bk8 + 3][brn] = bv0.w;
        Bs[bk8 + 4][brn] = bv1.x; Bs[bk8 + 5][brn] = bv1.y;
        Bs[bk8 + 6][brn] = bv1.z; Bs[bk8 + 7][brn] = bv1.w;
        __syncthreads();

#pragma unroll
        for (int kk = 0; kk < 16; ++kk) {
            float4 a4 = *(const float4*)&As[kk][ty * 4];
            float4 b40 = *(const float4*)&Bs[kk][tx * 8];
            float4 b41 = *(const float4*)&Bs[kk][tx * 8 + 4];
            float ai[4] = {a4.x, a4.y, a4.z, a4.w};
            float bj[8] = {b40.x, b40.y, b40.z, b40.w, b41.x, b41.y, b41.z, b41.w};
#pragma unroll
            for (int i = 0; i < 4; ++i)
#pragma unroll
                for (int j = 0; j < 8; ++j)
                    acc[i][j] += ai[i] * bj[j];
        }
    }

    const int nb = bn + tx * 8;
    float4 bi0 = *(const float4*)(b_ih + nb);
    float4 bi1 = *(const float4*)(b_ih + nb + 4);
    float4 bh0 = *(const float4*)(b_hh + nb);
    float4 bh1 = *(const float4*)(b_hh + nb + 4);
    float badd[8] = {bi0.x + bh0.x, bi0.y + bh0.y, bi0.z + bh0.z, bi0.w + bh0.w,
                     bi1.x + bh1.x, bi1.y + bh1.y, bi1.z + bh1.z, bi1.w + bh1.w};
#pragma unroll
    for (int i = 0; i < 4; ++i) {
        float4 o0, o1;
        o0.x = acc[i][0] + badd[0]; o0.y = acc[i][1] + badd[1];
        o0.z = acc[i][2] + badd[2]; o0.w = acc[i][3] + badd[3];
        o1.x = acc[i][4] + badd[4]; o1.y = acc[i][5] + badd[5];
        o1.z = acc[i][6] + badd[6]; o1.w = acc[i][7] + badd[7];
        float* Cp = gates + (long)(bm + ty * 4 + i) * 4096 + nb;
        *(float4*)(Cp) = o0;
        *(float4*)(Cp + 4) = o1;
    }
}

// ---------------------------------------------------------------------------
// Fused LSTM cell + LayerNorm. One block per b (256 threads, 4 d each).
// ---------------------------------------------------------------------------
__device__ __forceinline__ float sigm(float x) { return 1.0f / (1.0f + __expf(-x)); }

__global__ __launch_bounds__(256)
void lstm_ln(const float* __restrict__ gates, const float* __restrict__ cin,
             const float* __restrict__ ln_w, const float* __restrict__ ln_b,
             float* __restrict__ out0, float* __restrict__ out1)
{
    __shared__ float red[2][4];
    __shared__ float stats[2];

    const int b = blockIdx.x;
    const int tid = threadIdx.x;
    const int d4 = tid * 4;
    const float* g = gates + (long)b * 4096;

    float4 gi = *(const float4*)(g + d4);
    float4 gf = *(const float4*)(g + 1024 + d4);
    float4 gg = *(const float4*)(g + 2048 + d4);
    float4 go = *(const float4*)(g + 3072 + d4);
    float4 cv = *(const float4*)(cin + (long)b * kD + d4);

    float iv[4] = {gi.x, gi.y, gi.z, gi.w};
    float fv[4] = {gf.x, gf.y, gf.z, gf.w};
    float gv[4] = {gg.x, gg.y, gg.z, gg.w};
    float ov[4] = {go.x, go.y, go.z, go.w};
    float cc[4] = {cv.x, cv.y, cv.z, cv.w};

    float nc[4], nh[4];
#pragma unroll
    for (int u = 0; u < 4; ++u) {
        nc[u] = sigm(fv[u]) * cc[u] + sigm(iv[u]) * tanhf(gv[u]);
        nh[u] = sigm(ov[u]) * tanhf(nc[u]);
    }
    *(float4*)(out1 + (long)b * kD + d4) = make_float4(nc[0], nc[1], nc[2], nc[3]);

    float sum = nh[0] + nh[1] + nh[2] + nh[3];
    float ss  = nh[0]*nh[0] + nh[1]*nh[1] + nh[2]*nh[2] + nh[3]*nh[3];
#pragma unroll
    for (int m = 32; m >= 1; m >>= 1) {
        sum += __shfl_xor(sum, m);
        ss  += __shfl_xor(ss, m);
    }
    const int wave = tid >> 6, lane = tid & 63;
    if (lane == 0) { red[0][wave] = sum; red[1][wave] = ss; }
    __syncthreads();
    if (tid == 0) {
        float s = red[0][0] + red[0][1] + red[0][2] + red[0][3];
        float q = red[1][0] + red[1][1] + red[1][2] + red[1][3];
        float mu = s / (float)kD;
        float var = q / (float)kD - mu * mu;
        stats[0] = mu;
        stats[1] = rsqrtf(var + 1e-5f);
    }
    __syncthreads();
    const float mu = stats[0], rstd = stats[1];
    float4 lw = *(const float4*)(ln_w + d4);
    float4 lb = *(const float4*)(ln_b + d4);
    float lwv[4] = {lw.x, lw.y, lw.z, lw.w};
    float lbv[4] = {lb.x, lb.y, lb.z, lb.w};
    float o[4];
#pragma unroll
    for (int u = 0; u < 4; ++u)
        o[u] = (nh[u] - mu) * rstd * lwv[u] + lbv[u];
    *(float4*)(out0 + (long)b * kD + d4) = make_float4(o[0], o[1], o[2], o[3]);
}

// ---------------------------------------------------------------------------
extern "C" void kernel_launch(void* const* d_in, const int* in_sizes, int n_in,
                              void* d_out, int out_size, void* d_ws, size_t ws_size,
                              hipStream_t stream)
{
    (void)in_sizes; (void)n_in; (void)out_size;

    const float* h    = (const float*)d_in[0];
    const float* c    = (const float*)d_in[1];
    const float* xall = (const float*)d_in[2];
    const float* ext  = (const float*)d_in[3];
    const float* in_w = (const float*)d_in[4];
    const float* in_b = (const float*)d_in[5];
    const float* wo   = (const float*)d_in[6];
    const float* bo   = (const float*)d_in[7];
    const float* w_ih = (const float*)d_in[8];
    const float* b_ih = (const float*)d_in[9];
    const float* w_hh = (const float*)d_in[10];
    const float* b_hh = (const float*)d_in[11];
    const float* ln_w = (const float*)d_in[12];
    const float* ln_b = (const float*)d_in[13];

    float* out0 = (float*)d_out;              // LN(new_h) [512x1024]
    float* out1 = out0 + (long)kB * kD;       // new_c     [512x1024]

    // Workspace layout (floats)
    float* ws = (float*)d_ws;
    const size_t need = (size_t)(524288 + 1048576 + 1024 + 1048576 +
                                 524288 + 524288 + 2097152) * 4;
    if (ws_size < need) return;  // fail loudly (validation will catch)
    float* q      = ws;                    // [512 x 1024]
    float* qtl    = q      + 524288;       // [512 x 2 x 1024]
    float* sconst = qtl    + 1048576;      // [512 x 2]
    float* sacc   = sconst + 1024;         // [512 x 2 x 1024]
    float* ctx    = sacc   + 1048576;      // [512 x 1024]
    float* ctxp   = ctx    + 524288;       // [512 x 1024] context
    float* gates  = ctxp   + 524288;       // [512 x 4096]

    const float* wq = in_w;                       // rows 0..1023
    const float* wk = in_w + (long)kD * kD;       // rows 1024..2047
    const float* wv = in_w + 2L * kD * kD;        // rows 2048..3071
    const float* bq = in_b;
    const float* bk = in_b + kD;
    const float* bv = in_b + 2 * kD;

    // 1. q = h @ wq^T + bq
    gemm64<true><<<dim3(kD / 64, kB / 64, 1), 256, 0, stream>>>(
        kB, kD, kD, h, kD, 0, wq, kD, 0, q, kD, 0, bq, 0);

    // 2. sconst[b][h] = q_head . bk_head
    sconst_kernel<<<kB, 128, 0, stream>>>(q, bk, sconst);

    // 3. q-tilde: per head z: qt[:, z, :] = q_head @ wk_head  (NN)
    gemm64<false><<<dim3(kD / 64, kB / 64, 2), 256, 0, stream>>>(
        kB, kD, kDH, q, kD, (long)kDH, wk, kD, (long)kDH * kD,
        qtl, 2 * kD, (long)kD, nullptr, 0);

    // 4. fused attention -> weighted state sums s[b][h][:]
    attn_fused<<<kB, 512, 0, stream>>>(xall, qtl, sconst, sacc);

    // 5. ctx[:, h*512:...] = s_h @ wv_h^T + bv_h  (NT, per head)
    gemm64<true><<<dim3(kDH / 64, kB / 64, 2), 256, 0, stream>>>(
        kB, kDH, kD, sacc, 2 * kD, (long)kD, wv, kD, (long)kDH * kD,
        ctx, kD, (long)kDH, bv, (long)kDH);

    // 6. context = ctx @ wo^T + bo
    gemm64<true><<<dim3(kD / 64, kB / 64, 1), 256, 0, stream>>>(
        kB, kD, kD, ctx, kD, 0, wo, kD, 0, ctxp, kD, 0, bo, 0);

    // 7. gates = [context|ext] @ w_ih^T + h @ w_hh^T + b_ih + b_hh
    gates_gemm<<<dim3(4096 / 128, kB / 64), 256, 0, stream>>>(
        ctxp, ext, h, w_ih, w_hh, b_ih, b_hh, gates);

    // 8. LSTM cell + LayerNorm
    lstm_ln<<<kB, 256, 0, stream>>>(gates, c, ln_w, ln_b, out0, out1);
}

// Round 2
// 496.079 us; speedup vs baseline: 2.2246x; 2.2246x over previous
//
#include <hip/hip_runtime.h>
#include <math.h>
#include <stdint.h>

constexpr int kD  = 1024;   // model dim
constexpr int kB  = 512;    // batch
constexpr int kN  = 512;    // states per batch
constexpr int kDH = 512;    // head dim (H=2)

using bf16x8 = __attribute__((ext_vector_type(8))) short;
using f32x4v = __attribute__((ext_vector_type(4))) float;
using us8    = __attribute__((ext_vector_type(8))) unsigned short;

__device__ __forceinline__ unsigned short f2bf(float f) {
    uint32_t u = __float_as_uint(f);
    u += 0x7fffu + ((u >> 16) & 1u);     // round-to-nearest-even
    return (unsigned short)(u >> 16);
}

__device__ __forceinline__ void async16(const void* g, void* l) {
    __builtin_amdgcn_global_load_lds(
        (const __attribute__((address_space(1))) uint32_t*)g,
        (__attribute__((address_space(3))) uint32_t*)l, 16, 0, 0);
}

__device__ __forceinline__ void barrier_acq() {
    __builtin_amdgcn_s_barrier();
    asm volatile("" ::: "memory");
    __builtin_amdgcn_sched_barrier(0);
}

// ---------------------------------------------------------------------------
// f32 -> bf16 convert with optional column restride/offset.
// idx covers rows*scols/8 vectors of 8.
// ---------------------------------------------------------------------------
__global__ __launch_bounds__(256)
void cvt_bf16(const float* __restrict__ src, unsigned short* __restrict__ dst,
              int scols8, int dcols, int coloff, int n8)
{
    int idx = blockIdx.x * 256 + threadIdx.x;
    if (idx >= n8) return;
    int row = idx / scols8;
    int c = (idx - row * scols8) * 8;
    const float4* s = (const float4*)(src + (long)row * ((long)scols8 * 8) + c);
    float4 v0 = s[0], v1 = s[1];
    us8 o;
    o[0] = f2bf(v0.x); o[1] = f2bf(v0.y); o[2] = f2bf(v0.z); o[3] = f2bf(v0.w);
    o[4] = f2bf(v1.x); o[5] = f2bf(v1.y); o[6] = f2bf(v1.z); o[7] = f2bf(v1.w);
    *(us8*)(dst + (long)row * dcols + coloff + c) = o;
}

// ---------------------------------------------------------------------------
// wk transpose+convert: dst[h][n][k] = wk[h*512+k][n], dst bf16 [2][1024][512]
// ---------------------------------------------------------------------------
__global__ __launch_bounds__(256)
void tcvt_wk(const float* __restrict__ wk, unsigned short* __restrict__ dst)
{
    __shared__ float t[32][33];
    const int nt = blockIdx.x;     // 0..31 (n tiles)
    const int kt = blockIdx.y;     // 0..15 (k tiles)
    const int hh = blockIdx.z;     // head
    const int tx = threadIdx.x & 31, ty = threadIdx.x >> 5;   // 32 x 8
#pragma unroll
    for (int j = 0; j < 4; ++j)
        t[ty + j * 8][tx] = wk[(long)(hh * 512 + kt * 32 + ty + j * 8) * kD + nt * 32 + tx];
    __syncthreads();
#pragma unroll
    for (int j = 0; j < 4; ++j) {
        int n = nt * 32 + ty + j * 8;
        int k = kt * 32 + tx;
        dst[(long)hh * 524288 + (long)n * 512 + k] = f2bf(t[tx][ty + j * 8]);
    }
}

// ---------------------------------------------------------------------------
// badd = b_ih + b_hh  (4096)
// ---------------------------------------------------------------------------
__global__ __launch_bounds__(256)
void badd_kernel(const float* __restrict__ a, const float* __restrict__ b,
                 float* __restrict__ o)
{
    int i = blockIdx.x * 256 + threadIdx.x;
    if (i < 4096) o[i] = a[i] + b[i];
}

// ---------------------------------------------------------------------------
// bf16 MFMA GEMM, NT: C[m,n] = sum_k A[m,k]*B[n,k] (+bias[n]).
// 128x128 tile, BK=32, 256 threads (4 waves, 2x2), 16x16x32 MFMA.
// LDS layout [ksub][row][8] -> conflict-free ds_read_b128 fragments.
// z-batched via strides (elements).
// ---------------------------------------------------------------------------
__global__ __launch_bounds__(256)
void gemm_bf16_nt(const unsigned short* __restrict__ A, int lda, long sAz,
                  const unsigned short* __restrict__ B, int ldb, long sBz,
                  float* __restrict__ C, int ldc, long sCz,
                  const float* __restrict__ bias, long sbz, int K)
{
    __shared__ short As[4][128][8];
    __shared__ short Bs[4][128][8];
    A += (long)blockIdx.z * sAz;
    B += (long)blockIdx.z * sBz;
    C += (long)blockIdx.z * sCz;

    const int tid = threadIdx.x;
    const int l = tid & 63, w = tid >> 6;
    const int wr = w >> 1, wc = w & 1;
    const int bm = blockIdx.y * 128, bn = blockIdx.x * 128;

    f32x4v acc[4][4] = {};

    for (int k0 = 0; k0 < K; k0 += 32) {
        __syncthreads();
#pragma unroll
        for (int j = 0; j < 2; ++j) {
            int ca = j * 256 + tid;
            int ks = ca >> 7, r = ca & 127;
            async16(A + (long)(bm + r) * lda + k0 + ks * 8, (short*)As + (long)ca * 8);
            async16(B + (long)(bn + r) * ldb + k0 + ks * 8, (short*)Bs + (long)ca * 8);
        }
        __syncthreads();   // compiler drains vmcnt before barrier (m97 pattern)

        const int ks = l >> 4, rr = l & 15;
        bf16x8 a[4], b[4];
#pragma unroll
        for (int t = 0; t < 4; ++t) {
            a[t] = *(const bf16x8*)&As[ks][wr * 64 + t * 16 + rr][0];
            b[t] = *(const bf16x8*)&Bs[ks][wc * 64 + t * 16 + rr][0];
        }
#pragma unroll
        for (int mt = 0; mt < 4; ++mt)
#pragma unroll
            for (int nt = 0; nt < 4; ++nt)
                acc[mt][nt] = __builtin_amdgcn_mfma_f32_16x16x32_bf16(
                    a[mt], b[nt], acc[mt][nt], 0, 0, 0);
    }

    const int rr = l & 15, rg = l >> 4;
#pragma unroll
    for (int mt = 0; mt < 4; ++mt) {
#pragma unroll
        for (int nt = 0; nt < 4; ++nt) {
            const int n = bn + wc * 64 + nt * 16 + rr;
            float bb = bias ? bias[(long)blockIdx.z * sbz + n] : 0.f;
#pragma unroll
            for (int r = 0; r < 4; ++r) {
                const int m = bm + wr * 64 + mt * 16 + rg * 4 + r;
                C[(long)m * ldc + n] = acc[mt][nt][r] + bb;
            }
        }
    }
}

// ---------------------------------------------------------------------------
// sconst[b][h] = q[b, h*512 : ...] . bk[h*512 : ...]
// ---------------------------------------------------------------------------
__global__ __launch_bounds__(128)
void sconst_kernel(const float* __restrict__ q, const float* __restrict__ bk,
                   float* __restrict__ sconst)
{
    const int b = blockIdx.x;
    const int tid = threadIdx.x;
    const int h = tid >> 6, lane = tid & 63;
    float acc = 0.f;
#pragma unroll
    for (int i = 0; i < 8; ++i) {
        int j = lane + i * 64;
        acc += q[(long)b * kD + h * kDH + j] * bk[h * kDH + j];
    }
#pragma unroll
    for (int m = 32; m >= 1; m >>= 1) acc += __shfl_xor(acc, m);
    if (lane == 0) sconst[b * 2 + h] = acc;
}

// ---------------------------------------------------------------------------
// Fused attention, async double-buffered streaming pass.
// One block per b; 512 threads (8 waves). 8-row tiles, 2 LDS buffers (64 KB).
// Raw s_barrier + explicit waitcnt so the tile-(t+1) prefetch stays in flight
// across the mid-tile barrier (T3/T4 counted-vmcnt pattern).
// ---------------------------------------------------------------------------
constexpr int kR = 8;   // rows per tile
__global__ __launch_bounds__(512, 4)
void attn2(const float* __restrict__ xall,   // [B][N][D] f32
           const float* __restrict__ qt,     // [B][2][D] f32
           const float* __restrict__ sconst, // [B][2]
           float* __restrict__ sout)         // [B][2][D]
{
    __shared__ float X[2][kR][kD];           // 2 x 32 KB
    __shared__ float sc[2][kR];

    const int b = blockIdx.x;
    const int tid = threadIdx.x;
    const int w = tid >> 6, l = tid & 63;
    const int h = tid >> 8;                  // head owned for accumulation
    const int d0 = (tid & 255) * 4;
    const float scale = 0.044194173824159216f;   // 1/sqrt(512)

    // q-tilde fragments: pair with x element d = l + 64*j
    float qr0[16], qr1[16];
    const float* qb = qt + (long)b * 2 * kD;
#pragma unroll
    for (int j = 0; j < 16; ++j) {
        qr0[j] = qb[l + 64 * j];
        qr1[j] = qb[kD + l + 64 * j];
    }
    const float qbk0 = sconst[b * 2 + 0];
    const float qbk1 = sconst[b * 2 + 1];

    float m_run = -1e30f, l_run = 0.f;
    float s0 = 0.f, s1 = 0.f, s2 = 0.f, s3 = 0.f;

    const char* xbase = (const char*)(xall + (long)b * kN * kD);

#define STAGE(tt, bufi) do {                                              \
        const char* srcb = xbase + (long)(tt) * 32768;                    \
        char* dstb = (char*)&X[bufi][0][0];                               \
        _Pragma("unroll")                                                 \
        for (int j = 0; j < 4; ++j) {                                     \
            int chunk = j * 512 + tid;                                    \
            async16(srcb + (long)chunk * 16, dstb + (long)chunk * 16);    \
        }                                                                 \
    } while (0)

    STAGE(0, 0);

    for (int t = 0; t < kN / kR; ++t) {
        const int cur = t & 1;
        asm volatile("s_waitcnt vmcnt(0)" ::: "memory");   // buf[cur] arrived
        barrier_acq();                                     // all waves done w/ buf[cur^1]
        if (t + 1 < kN / kR) STAGE(t + 1, cur ^ 1);        // prefetch stays in flight

        // ---- phase A: wave w computes scores for row w (both heads)
        float a0 = 0.f, a1 = 0.f;
#pragma unroll
        for (int j = 0; j < 16; ++j) {
            float xv = X[cur][w][l + 64 * j];
            a0 += xv * qr0[j];
            a1 += xv * qr1[j];
        }
#pragma unroll
        for (int m = 32; m >= 1; m >>= 1) {
            a0 += __shfl_xor(a0, m);
            a1 += __shfl_xor(a1, m);
        }
        if (l == 0) {
            sc[0][w] = (a0 + qbk0) * scale;
            sc[1][w] = (a1 + qbk1) * scale;
        }
        asm volatile("s_waitcnt lgkmcnt(0)" ::: "memory");
        barrier_acq();                                     // sc visible

        // ---- redundant per-thread online-softmax update for own head
        float v[kR];
#pragma unroll
        for (int n = 0; n < kR; ++n) v[n] = sc[h][n];
        float mx = v[0];
#pragma unroll
        for (int n = 1; n < kR; ++n) mx = fmaxf(mx, v[n]);
        float mnew = fmaxf(m_run, mx);
        float r = __expf(m_run - mnew);
        float p[kR], psum = 0.f;
#pragma unroll
        for (int n = 0; n < kR; ++n) { p[n] = __expf(v[n] - mnew); psum += p[n]; }
        l_run = l_run * r + psum;
        m_run = mnew;
        s0 *= r; s1 *= r; s2 *= r; s3 *= r;

        // ---- phase B: weighted accumulate of raw states
#pragma unroll
        for (int n = 0; n < kR; ++n) {
            float4 xv = *(const float4*)&X[cur][n][d0];
            s0 += p[n] * xv.x; s1 += p[n] * xv.y;
            s2 += p[n] * xv.z; s3 += p[n] * xv.w;
        }
    }
#undef STAGE

    const float inv = 1.0f / l_run;
    *(float4*)(sout + (long)b * 2 * kD + h * kD + d0) =
        make_float4(s0 * inv, s1 * inv, s2 * inv, s3 * inv);
}

// ---------------------------------------------------------------------------
// Fused LSTM cell + LayerNorm. One block per b (256 threads, 4 d each).
// ---------------------------------------------------------------------------
__device__ __forceinline__ float sigm(float x) { return 1.0f / (1.0f + __expf(-x)); }

__global__ __launch_bounds__(256)
void lstm_ln(const float* __restrict__ gates, const float* __restrict__ cin,
             const float* __restrict__ ln_w, const float* __restrict__ ln_b,
             float* __restrict__ out0, float* __restrict__ out1)
{
    __shared__ float red[2][4];
    __shared__ float stats[2];

    const int b = blockIdx.x;
    const int tid = threadIdx.x;
    const int d4 = tid * 4;
    const float* g = gates + (long)b * 4096;

    float4 gi = *(const float4*)(g + d4);
    float4 gf = *(const float4*)(g + 1024 + d4);
    float4 gg = *(const float4*)(g + 2048 + d4);
    float4 go = *(const float4*)(g + 3072 + d4);
    float4 cv = *(const float4*)(cin + (long)b * kD + d4);

    float iv[4] = {gi.x, gi.y, gi.z, gi.w};
    float fv[4] = {gf.x, gf.y, gf.z, gf.w};
    float gv[4] = {gg.x, gg.y, gg.z, gg.w};
    float ov[4] = {go.x, go.y, go.z, go.w};
    float cc[4] = {cv.x, cv.y, cv.z, cv.w};

    float nc[4], nh[4];
#pragma unroll
    for (int u = 0; u < 4; ++u) {
        nc[u] = sigm(fv[u]) * cc[u] + sigm(iv[u]) * tanhf(gv[u]);
        nh[u] = sigm(ov[u]) * tanhf(nc[u]);
    }
    *(float4*)(out1 + (long)b * kD + d4) = make_float4(nc[0], nc[1], nc[2], nc[3]);

    float sum = nh[0] + nh[1] + nh[2] + nh[3];
    float ss  = nh[0]*nh[0] + nh[1]*nh[1] + nh[2]*nh[2] + nh[3]*nh[3];
#pragma unroll
    for (int m = 32; m >= 1; m >>= 1) {
        sum += __shfl_xor(sum, m);
        ss  += __shfl_xor(ss, m);
    }
    const int wave = tid >> 6, lane = tid & 63;
    if (lane == 0) { red[0][wave] = sum; red[1][wave] = ss; }
    __syncthreads();
    if (tid == 0) {
        float s = red[0][0] + red[0][1] + red[0][2] + red[0][3];
        float q = red[1][0] + red[1][1] + red[1][2] + red[1][3];
        float mu = s / (float)kD;
        float var = q / (float)kD - mu * mu;
        stats[0] = mu;
        stats[1] = rsqrtf(var + 1e-5f);
    }
    __syncthreads();
    const float mu = stats[0], rstd = stats[1];
    float4 lw = *(const float4*)(ln_w + d4);
    float4 lb = *(const float4*)(ln_b + d4);
    float lwv[4] = {lw.x, lw.y, lw.z, lw.w};
    float lbv[4] = {lb.x, lb.y, lb.z, lb.w};
    float o[4];
#pragma unroll
    for (int u = 0; u < 4; ++u)
        o[u] = (nh[u] - mu) * rstd * lwv[u] + lbv[u];
    *(float4*)(out0 + (long)b * kD + d4) = make_float4(o[0], o[1], o[2], o[3]);
}

// ---------------------------------------------------------------------------
extern "C" void kernel_launch(void* const* d_in, const int* in_sizes, int n_in,
                              void* d_out, int out_size, void* d_ws, size_t ws_size,
                              hipStream_t stream)
{
    (void)in_sizes; (void)n_in; (void)out_size;

    const float* h    = (const float*)d_in[0];
    const float* c    = (const float*)d_in[1];
    const float* xall = (const float*)d_in[2];
    const float* ext  = (const float*)d_in[3];
    const float* in_w = (const float*)d_in[4];
    const float* in_b = (const float*)d_in[5];
    const float* wo   = (const float*)d_in[6];
    const float* bo   = (const float*)d_in[7];
    const float* w_ih = (const float*)d_in[8];
    const float* b_ih = (const float*)d_in[9];
    const float* w_hh = (const float*)d_in[10];
    const float* b_hh = (const float*)d_in[11];
    const float* ln_w = (const float*)d_in[12];
    const float* ln_b = (const float*)d_in[13];

    float* out0 = (float*)d_out;              // LN(new_h) [512x1024]
    float* out1 = out0 + (long)kB * kD;       // new_c     [512x1024]

    // ---- workspace layout (bytes; all chunks 16B-aligned)
    char* p = (char*)d_ws;
    const size_t need = 23089152ull + 40894208ull;
    if (ws_size < need) return;

    float* q      = (float*)p; p += 2097152;   // [512][1024]
    float* qtl    = (float*)p; p += 4194304;   // [512][2][1024]
    float* sacc   = (float*)p; p += 4194304;   // [512][2][1024]
    float* ctx    = (float*)p; p += 2097152;   // [512][1024]
    float* ctxp   = (float*)p; p += 2097152;   // [512][1024]
    float* gates  = (float*)p; p += 8388608;   // [512][4096]
    float* sconst = (float*)p; p += 4096;      // [512][2]
    float* badd   = (float*)p; p += 16384;     // [4096]

    unsigned short* h_bf   = (unsigned short*)p; p += 1048576;   // [512][1024]
    unsigned short* wq_bf  = (unsigned short*)p; p += 2097152;   // [1024][1024]
    unsigned short* wkT_bf = (unsigned short*)p; p += 2097152;   // [2][1024][512]
    unsigned short* wv_bf  = (unsigned short*)p; p += 2097152;   // [1024][1024]
    unsigned short* wo_bf  = (unsigned short*)p; p += 2097152;   // [1024][1024]
    unsigned short* q_bf   = (unsigned short*)p; p += 1048576;   // [512][1024]
    unsigned short* sac_bf = (unsigned short*)p; p += 2097152;   // [512][2048]
    unsigned short* ctx_bf = (unsigned short*)p; p += 1048576;   // [512][1024]
    unsigned short* acat   = (unsigned short*)p; p += 3145728;   // [512][3072]
    unsigned short* wcat   = (unsigned short*)p; p += 25165824;  // [4096][3072]

    const float* wk_f = in_w + (long)kD * kD;       // rows 1024..2047
    const float* bq = in_b;
    const float* bk = in_b + kD;
    const float* bv = in_b + 2 * kD;

    auto cvt = [&](const float* src, unsigned short* dst, int rows, int scols,
                   int dcols, int coloff) {
        int n8 = rows * (scols / 8);
        cvt_bf16<<<(n8 + 255) / 256, 256, 0, stream>>>(src, dst, scols / 8, dcols, coloff, n8);
    };

    // ---- weight / input conversions
    badd_kernel<<<16, 256, 0, stream>>>(b_ih, b_hh, badd);
    cvt(h, h_bf, 512, 1024, 1024, 0);
    cvt(in_w, wq_bf, 1024, 1024, 1024, 0);
    tcvt_wk<<<dim3(32, 16, 2), 256, 0, stream>>>(wk_f, wkT_bf);
    cvt(in_w + 2L * kD * kD, wv_bf, 1024, 1024, 1024, 0);
    cvt(wo, wo_bf, 1024, 1024, 1024, 0);
    cvt(w_ih, wcat, 4096, 2048, 3072, 0);
    cvt(w_hh, wcat, 4096, 1024, 3072, 2048);

    // 1. q = h @ wq^T + bq
    gemm_bf16_nt<<<dim3(8, 4, 1), 256, 0, stream>>>(
        h_bf, 1024, 0, wq_bf, 1024, 0, q, 1024, 0, bq, 0, 1024);

    // 2. sconst[b][h] = q_head . bk_head
    sconst_kernel<<<kB, 128, 0, stream>>>(q, bk, sconst);

    // 3. q-tilde: qtl[:, z, :] = q_z @ wkT_z^T(NT)
    cvt(q, q_bf, 512, 1024, 1024, 0);
    gemm_bf16_nt<<<dim3(8, 4, 2), 256, 0, stream>>>(
        q_bf, 1024, 512, wkT_bf, 512, 524288, qtl, 2048, 1024, nullptr, 0, 512);

    // 4. fused attention -> weighted state sums
    attn2<<<kB, 512, 0, stream>>>(xall, qtl, sconst, sacc);

    // 5. ctx[:, z*512:...] = s_z @ wv_z^T + bv_z
    cvt(sacc, sac_bf, 512, 2048, 2048, 0);
    gemm_bf16_nt<<<dim3(4, 4, 2), 256, 0, stream>>>(
        sac_bf, 2048, 1024, wv_bf, 1024, 524288, ctx, 1024, 512, bv, 512, 1024);

    // 6. context = ctx @ wo^T + bo
    cvt(ctx, ctx_bf, 512, 1024, 1024, 0);
    gemm_bf16_nt<<<dim3(8, 4, 1), 256, 0, stream>>>(
        ctx_bf, 1024, 0, wo_bf, 1024, 0, ctxp, 1024, 0, bo, 0, 1024);

    // 7. gates = [context|ext|h] @ [w_ih|w_hh]^T + (b_ih + b_hh)
    cvt(ctxp, acat, 512, 1024, 3072, 0);
    cvt(ext,  acat, 512, 1024, 3072, 1024);
    cvt(h,    acat, 512, 1024, 3072, 2048);
    gemm_bf16_nt<<<dim3(32, 4, 1), 256, 0, stream>>>(
        acat, 3072, 0, wcat, 3072, 0, gates, 4096, 0, badd, 0, 3072);

    // 8. LSTM cell + LayerNorm
    lstm_ln<<<kB, 256, 0, stream>>>(gates, c, ln_w, ln_b, out0, out1);
}

// Round 3
// 450.711 us; speedup vs baseline: 2.4485x; 1.1007x over previous
//
#include <hip/hip_runtime.h>
#include <math.h>
#include <stdint.h>

constexpr int kD  = 1024;   // model dim
constexpr int kB  = 512;    // batch
constexpr int kN  = 512;    // states per batch
constexpr int kDH = 512;    // head dim (H=2)

using bf16x8 = __attribute__((ext_vector_type(8))) short;
using f32x4v = __attribute__((ext_vector_type(4))) float;
using us8    = __attribute__((ext_vector_type(8))) unsigned short;

__device__ __forceinline__ unsigned short f2bf(float f) {
    uint32_t u = __float_as_uint(f);
    u += 0x7fffu + ((u >> 16) & 1u);     // round-to-nearest-even
    return (unsigned short)(u >> 16);
}

__device__ __forceinline__ void async16(const void* g, void* l) {
    __builtin_amdgcn_global_load_lds(
        (const __attribute__((address_space(1))) uint32_t*)g,
        (__attribute__((address_space(3))) uint32_t*)l, 16, 0, 0);
}

__device__ __forceinline__ void barrier_acq() {
    __builtin_amdgcn_s_barrier();
    asm volatile("" ::: "memory");
    __builtin_amdgcn_sched_barrier(0);
}

// ---------------------------------------------------------------------------
// f32 -> bf16 convert with optional column restride/offset.
// ---------------------------------------------------------------------------
__global__ __launch_bounds__(256)
void cvt_bf16(const float* __restrict__ src, unsigned short* __restrict__ dst,
              int scols8, int dcols, int coloff, int n8)
{
    int idx = blockIdx.x * 256 + threadIdx.x;
    if (idx >= n8) return;
    int row = idx / scols8;
    int c = (idx - row * scols8) * 8;
    const float4* s = (const float4*)(src + (long)row * ((long)scols8 * 8) + c);
    float4 v0 = s[0], v1 = s[1];
    us8 o;
    o[0] = f2bf(v0.x); o[1] = f2bf(v0.y); o[2] = f2bf(v0.z); o[3] = f2bf(v0.w);
    o[4] = f2bf(v1.x); o[5] = f2bf(v1.y); o[6] = f2bf(v1.z); o[7] = f2bf(v1.w);
    *(us8*)(dst + (long)row * dcols + coloff + c) = o;
}

// ---------------------------------------------------------------------------
// wk transpose+convert: dst[h][n][k] = wk[h*512+k][n], dst bf16 [2][1024][512]
// ---------------------------------------------------------------------------
__global__ __launch_bounds__(256)
void tcvt_wk(const float* __restrict__ wk, unsigned short* __restrict__ dst)
{
    __shared__ float t[32][33];
    const int nt = blockIdx.x;     // 0..31 (n tiles)
    const int kt = blockIdx.y;     // 0..15 (k tiles)
    const int hh = blockIdx.z;     // head
    const int tx = threadIdx.x & 31, ty = threadIdx.x >> 5;   // 32 x 8
#pragma unroll
    for (int j = 0; j < 4; ++j)
        t[ty + j * 8][tx] = wk[(long)(hh * 512 + kt * 32 + ty + j * 8) * kD + nt * 32 + tx];
    __syncthreads();
#pragma unroll
    for (int j = 0; j < 4; ++j) {
        int n = nt * 32 + ty + j * 8;
        int k = kt * 32 + tx;
        dst[(long)hh * 524288 + (long)n * 512 + k] = f2bf(t[tx][ty + j * 8]);
    }
}

__global__ __launch_bounds__(256)
void badd_kernel(const float* __restrict__ a, const float* __restrict__ b,
                 float* __restrict__ o)
{
    int i = blockIdx.x * 256 + threadIdx.x;
    if (i < 4096) o[i] = a[i] + b[i];
}

// ---------------------------------------------------------------------------
// bf16 MFMA GEMM, NT: C[m,n] = sum_k A[m,k]*B[n,k] (+bias[n]).
// 64x128 tile, BK=32, 256 threads (4 waves, 2x2 of 32x64), 16x16x32 MFMA.
// Optional f32 and/or bf16 outputs. z-batched via element strides.
// ---------------------------------------------------------------------------
__global__ __launch_bounds__(256)
void gemm_bf16(const unsigned short* __restrict__ A, int lda, long sAz,
               const unsigned short* __restrict__ B, int ldb, long sBz,
               float* __restrict__ Cf, int ldcf, long sCfz,
               unsigned short* __restrict__ Cb, int ldcb, long sCbz,
               const float* __restrict__ bias, long sbz, int K)
{
    __shared__ short As[4][64][8];
    __shared__ short Bs[4][128][8];
    A += (long)blockIdx.z * sAz;
    B += (long)blockIdx.z * sBz;

    const int tid = threadIdx.x;
    const int l = tid & 63, w = tid >> 6;
    const int wr = w >> 1, wc = w & 1;
    const int bm = blockIdx.y * 64, bn = blockIdx.x * 128;

    f32x4v acc[2][4] = {};

    for (int k0 = 0; k0 < K; k0 += 32) {
        __syncthreads();
        {
            int ks = tid >> 6, r = tid & 63;
            async16(A + (long)(bm + r) * lda + k0 + ks * 8, (short*)As + (long)tid * 8);
        }
#pragma unroll
        for (int j = 0; j < 2; ++j) {
            int ca = j * 256 + tid;
            int ks = ca >> 7, r = ca & 127;
            async16(B + (long)(bn + r) * ldb + k0 + ks * 8, (short*)Bs + (long)ca * 8);
        }
        __syncthreads();   // compiler drains vmcnt before barrier (m97 pattern)

        const int ks = l >> 4, rr = l & 15;
        bf16x8 a[2], b[4];
#pragma unroll
        for (int t = 0; t < 2; ++t)
            a[t] = *(const bf16x8*)&As[ks][wr * 32 + t * 16 + rr][0];
#pragma unroll
        for (int t = 0; t < 4; ++t)
            b[t] = *(const bf16x8*)&Bs[ks][wc * 64 + t * 16 + rr][0];
#pragma unroll
        for (int mt = 0; mt < 2; ++mt)
#pragma unroll
            for (int nt = 0; nt < 4; ++nt)
                acc[mt][nt] = __builtin_amdgcn_mfma_f32_16x16x32_bf16(
                    a[mt], b[nt], acc[mt][nt], 0, 0, 0);
    }

    const int rr = l & 15, rg = l >> 4;
#pragma unroll
    for (int mt = 0; mt < 2; ++mt) {
#pragma unroll
        for (int nt = 0; nt < 4; ++nt) {
            const int n = bn + wc * 64 + nt * 16 + rr;
            float bb = bias ? bias[(long)blockIdx.z * sbz + n] : 0.f;
#pragma unroll
            for (int r = 0; r < 4; ++r) {
                const int m = bm + wr * 32 + mt * 16 + rg * 4 + r;
                float val = acc[mt][nt][r] + bb;
                if (Cf) Cf[(long)blockIdx.z * sCfz + (long)m * ldcf + n] = val;
                if (Cb) Cb[(long)blockIdx.z * sCbz + (long)m * ldcb + n] = f2bf(val);
            }
        }
    }
}

// ---------------------------------------------------------------------------
// Fused attention, N split 4-way. Block = (b, chunk of 128 states).
// 512 threads, kR=4-row tiles (16 KB), double-buffered async staging
// (32 KB LDS -> 4 blocks/CU -> ~64 KB HBM in flight per CU).
// Online softmax per thread (redundant per head); unnormalized partials out.
// Note: q.b_k is softmax-shift-invariant and omitted.
// ---------------------------------------------------------------------------
constexpr int kR = 4;       // rows per tile
constexpr int kSPL = 4;     // N splits
__global__ __launch_bounds__(512, 6)
void attn3(const float* __restrict__ xall,   // [B][N][D]
           const float* __restrict__ qt,     // [B][2][D]
           float* __restrict__ spart,        // [B][kSPL][2][D] unnormalized
           float* __restrict__ mlpart)       // [B][kSPL][2][2]
{
    __shared__ float X[2][kR][kD];           // 2 x 16 KB
    __shared__ float scp[2][kR][2];          // [head][row][half]

    const int bid = blockIdx.x;
    const int b = bid >> 2, cs = bid & 3;
    const int tid = threadIdx.x;
    const int w = tid >> 6, l = tid & 63;
    const int row = w >> 1, hf = w & 1;      // phase-A assignment
    const int h = tid >> 8, d0 = (tid & 255) * 4;   // phase-B assignment
    const float scale = 0.044194173824159216f;      // 1/sqrt(512)

    // q-tilde registers for phase A: qr[h][j] pairs with x[hf*512 + l*8 + j]
    float qr0[8], qr1[8];
    {
        const float* qb = qt + (long)b * 2 * kD + hf * 512 + l * 8;
        float4 a0 = *(const float4*)(qb);
        float4 a1 = *(const float4*)(qb + 4);
        float4 b0 = *(const float4*)(qb + kD);
        float4 b1 = *(const float4*)(qb + kD + 4);
        qr0[0]=a0.x; qr0[1]=a0.y; qr0[2]=a0.z; qr0[3]=a0.w;
        qr0[4]=a1.x; qr0[5]=a1.y; qr0[6]=a1.z; qr0[7]=a1.w;
        qr1[0]=b0.x; qr1[1]=b0.y; qr1[2]=b0.z; qr1[3]=b0.w;
        qr1[4]=b1.x; qr1[5]=b1.y; qr1[6]=b1.z; qr1[7]=b1.w;
    }

    float m_run = -1e30f, l_run = 0.f;
    float s0 = 0.f, s1 = 0.f, s2 = 0.f, s3 = 0.f;

    const char* xbase = (const char*)(xall + (long)b * kN * kD + (long)cs * 128 * kD);

#define STAGE(tt, bufi) do {                                              \
        const char* srcb = xbase + (long)(tt) * 16384;                    \
        char* dstb = (char*)&X[bufi][0][0];                               \
        _Pragma("unroll")                                                 \
        for (int j = 0; j < 2; ++j) {                                     \
            int chunk = j * 512 + tid;                                    \
            async16(srcb + (long)chunk * 16, dstb + (long)chunk * 16);    \
        }                                                                 \
    } while (0)

    STAGE(0, 0);

    constexpr int nT = 128 / kR;   // 32 tiles
    for (int t = 0; t < nT; ++t) {
        const int cur = t & 1;
        asm volatile("s_waitcnt vmcnt(0)" ::: "memory");   // buf[cur] arrived
        barrier_acq();                                     // everyone done with buf[cur^1]
        if (t + 1 < nT) STAGE(t + 1, cur ^ 1);             // prefetch stays in flight

        // ---- phase A: wave (row, half) computes half-row dots, both heads
        {
            const float* xr = &X[cur][row][hf * 512 + l * 8];
            float4 x0 = *(const float4*)(xr);
            float4 x1 = *(const float4*)(xr + 4);
            float xa[8] = {x0.x, x0.y, x0.z, x0.w, x1.x, x1.y, x1.z, x1.w};
            float a0 = 0.f, a1 = 0.f;
#pragma unroll
            for (int j = 0; j < 8; ++j) {
                a0 += xa[j] * qr0[j];
                a1 += xa[j] * qr1[j];
            }
#pragma unroll
            for (int m = 32; m >= 1; m >>= 1) {
                a0 += __shfl_xor(a0, m);
                a1 += __shfl_xor(a1, m);
            }
            if (l == 0) {
                scp[0][row][hf] = a0;
                scp[1][row][hf] = a1;
            }
        }
        asm volatile("s_waitcnt lgkmcnt(0)" ::: "memory");
        barrier_acq();                                     // scp visible

        // ---- per-thread online softmax for own head
        float v[kR];
#pragma unroll
        for (int n = 0; n < kR; ++n)
            v[n] = (scp[h][n][0] + scp[h][n][1]) * scale;
        float mx = v[0];
#pragma unroll
        for (int n = 1; n < kR; ++n) mx = fmaxf(mx, v[n]);
        float mnew = fmaxf(m_run, mx);
        float r = __expf(m_run - mnew);
        float p[kR], psum = 0.f;
#pragma unroll
        for (int n = 0; n < kR; ++n) { p[n] = __expf(v[n] - mnew); psum += p[n]; }
        l_run = l_run * r + psum;
        m_run = mnew;
        s0 *= r; s1 *= r; s2 *= r; s3 *= r;

        // ---- phase B: weighted accumulate of raw states
#pragma unroll
        for (int n = 0; n < kR; ++n) {
            float4 xv = *(const float4*)&X[cur][n][d0];
            s0 += p[n] * xv.x; s1 += p[n] * xv.y;
            s2 += p[n] * xv.z; s3 += p[n] * xv.w;
        }
    }
#undef STAGE

    // unnormalized partials + (m, l)
    *(float4*)(spart + (((long)b * kSPL + cs) * 2 + h) * kD + d0) =
        make_float4(s0, s1, s2, s3);
    if ((tid & 255) == 0) {
        float* mlp = mlpart + (long)b * 16 + cs * 4 + h * 2;
        mlp[0] = m_run;
        mlp[1] = l_run;
    }
}

// ---------------------------------------------------------------------------
// Combine 4 partials -> normalized context-state sums, written as bf16
// directly into the GEMM-5 A operand layout [B][2*D].
// ---------------------------------------------------------------------------
__global__ __launch_bounds__(256)
void attn_combine(const float* __restrict__ spart, const float* __restrict__ mlpart,
                  unsigned short* __restrict__ sac_bf)
{
    const int b = blockIdx.x;
    const int tid = threadIdx.x;
    const int h = tid >> 7, d0 = (tid & 127) * 8;

    const float* mlb = mlpart + (long)b * 16 + h * 2;
    float m[kSPL], lv[kSPL];
#pragma unroll
    for (int c = 0; c < kSPL; ++c) { m[c] = mlb[c * 4]; lv[c] = mlb[c * 4 + 1]; }
    float ms = m[0];
#pragma unroll
    for (int c = 1; c < kSPL; ++c) ms = fmaxf(ms, m[c]);
    float wgt[kSPL], L = 0.f;
#pragma unroll
    for (int c = 0; c < kSPL; ++c) { wgt[c] = __expf(m[c] - ms); L += wgt[c] * lv[c]; }
    const float inv = 1.0f / L;

    float acc[8] = {};
#pragma unroll
    for (int c = 0; c < kSPL; ++c) {
        const float4* sp = (const float4*)(spart + (((long)b * kSPL + c) * 2 + h) * kD + d0);
        float4 a = sp[0], bq = sp[1];
        acc[0] += wgt[c] * a.x;  acc[1] += wgt[c] * a.y;
        acc[2] += wgt[c] * a.z;  acc[3] += wgt[c] * a.w;
        acc[4] += wgt[c] * bq.x; acc[5] += wgt[c] * bq.y;
        acc[6] += wgt[c] * bq.z; acc[7] += wgt[c] * bq.w;
    }
    us8 o;
#pragma unroll
    for (int j = 0; j < 8; ++j) o[j] = f2bf(acc[j] * inv);
    *(us8*)(sac_bf + (long)b * 2048 + h * kD + d0) = o;
}

// ---------------------------------------------------------------------------
// Fused LSTM cell + LayerNorm. One block per b (256 threads, 4 d each).
// ---------------------------------------------------------------------------
__device__ __forceinline__ float sigm(float x) { return 1.0f / (1.0f + __expf(-x)); }

__global__ __launch_bounds__(256)
void lstm_ln(const float* __restrict__ gates, const float* __restrict__ cin,
             const float* __restrict__ ln_w, const float* __restrict__ ln_b,
             float* __restrict__ out0, float* __restrict__ out1)
{
    __shared__ float red[2][4];
    __shared__ float stats[2];

    const int b = blockIdx.x;
    const int tid = threadIdx.x;
    const int d4 = tid * 4;
    const float* g = gates + (long)b * 4096;

    float4 gi = *(const float4*)(g + d4);
    float4 gf = *(const float4*)(g + 1024 + d4);
    float4 gg = *(const float4*)(g + 2048 + d4);
    float4 go = *(const float4*)(g + 3072 + d4);
    float4 cv = *(const float4*)(cin + (long)b * kD + d4);

    float iv[4] = {gi.x, gi.y, gi.z, gi.w};
    float fv[4] = {gf.x, gf.y, gf.z, gf.w};
    float gv[4] = {gg.x, gg.y, gg.z, gg.w};
    float ov[4] = {go.x, go.y, go.z, go.w};
    float cc[4] = {cv.x, cv.y, cv.z, cv.w};

    float nc[4], nh[4];
#pragma unroll
    for (int u = 0; u < 4; ++u) {
        nc[u] = sigm(fv[u]) * cc[u] + sigm(iv[u]) * tanhf(gv[u]);
        nh[u] = sigm(ov[u]) * tanhf(nc[u]);
    }
    *(float4*)(out1 + (long)b * kD + d4) = make_float4(nc[0], nc[1], nc[2], nc[3]);

    float sum = nh[0] + nh[1] + nh[2] + nh[3];
    float ss  = nh[0]*nh[0] + nh[1]*nh[1] + nh[2]*nh[2] + nh[3]*nh[3];
#pragma unroll
    for (int m = 32; m >= 1; m >>= 1) {
        sum += __shfl_xor(sum, m);
        ss  += __shfl_xor(ss, m);
    }
    const int wave = tid >> 6, lane = tid & 63;
    if (lane == 0) { red[0][wave] = sum; red[1][wave] = ss; }
    __syncthreads();
    if (tid == 0) {
        float s = red[0][0] + red[0][1] + red[0][2] + red[0][3];
        float q = red[1][0] + red[1][1] + red[1][2] + red[1][3];
        float mu = s / (float)kD;
        float var = q / (float)kD - mu * mu;
        stats[0] = mu;
        stats[1] = rsqrtf(var + 1e-5f);
    }
    __syncthreads();
    const float mu = stats[0], rstd = stats[1];
    float4 lw = *(const float4*)(ln_w + d4);
    float4 lb = *(const float4*)(ln_b + d4);
    float lwv[4] = {lw.x, lw.y, lw.z, lw.w};
    float lbv[4] = {lb.x, lb.y, lb.z, lb.w};
    float o[4];
#pragma unroll
    for (int u = 0; u < 4; ++u)
        o[u] = (nh[u] - mu) * rstd * lwv[u] + lbv[u];
    *(float4*)(out0 + (long)b * kD + d4) = make_float4(o[0], o[1], o[2], o[3]);
}

// ---------------------------------------------------------------------------
extern "C" void kernel_launch(void* const* d_in, const int* in_sizes, int n_in,
                              void* d_out, int out_size, void* d_ws, size_t ws_size,
                              hipStream_t stream)
{
    (void)in_sizes; (void)n_in; (void)out_size;

    const float* h    = (const float*)d_in[0];
    const float* c    = (const float*)d_in[1];
    const float* xall = (const float*)d_in[2];
    const float* ext  = (const float*)d_in[3];
    const float* in_w = (const float*)d_in[4];
    const float* in_b = (const float*)d_in[5];
    const float* wo   = (const float*)d_in[6];
    const float* bo   = (const float*)d_in[7];
    const float* w_ih = (const float*)d_in[8];
    const float* b_ih = (const float*)d_in[9];
    const float* w_hh = (const float*)d_in[10];
    const float* b_hh = (const float*)d_in[11];
    const float* ln_w = (const float*)d_in[12];
    const float* ln_b = (const float*)d_in[13];

    float* out0 = (float*)d_out;              // LN(new_h) [512x1024]
    float* out1 = out0 + (long)kB * kD;       // new_c     [512x1024]

    // ---- workspace layout (bytes; 16B-aligned chunks)
    char* p = (char*)d_ws;
    const size_t need = 62963712ull;
    if (ws_size < need) return;

    float*          badd   = (float*)p;          p += 16384;     // [4096]
    unsigned short* h_bf   = (unsigned short*)p; p += 1048576;   // [512][1024]
    unsigned short* wq_bf  = (unsigned short*)p; p += 2097152;   // [1024][1024]
    unsigned short* wkT_bf = (unsigned short*)p; p += 2097152;   // [2][1024][512]
    unsigned short* wv_bf  = (unsigned short*)p; p += 2097152;   // [1024][1024]
    unsigned short* wo_bf  = (unsigned short*)p; p += 2097152;   // [1024][1024]
    unsigned short* q_bf   = (unsigned short*)p; p += 1048576;   // [512][1024]
    unsigned short* sac_bf = (unsigned short*)p; p += 2097152;   // [512][2048]
    unsigned short* ctx_bf = (unsigned short*)p; p += 1048576;   // [512][1024]
    unsigned short* acat   = (unsigned short*)p; p += 3145728;   // [512][3072]
    unsigned short* wcat   = (unsigned short*)p; p += 25165824;  // [4096][3072]
    // overlay region: {qtl, spart, mlpart} (attention phase) / {gates} (later)
    char* ov = p;
    float* qtl    = (float*)ov;                  // [512][2][1024]  f32
    float* spart  = (float*)(ov + 4194304);      // [512][4][2][1024]
    float* mlpart = (float*)(ov + 4194304 + 16777216);  // [512][4][2][2]
    float* gates  = (float*)ov;                  // [512][4096] (aliases, later)

    const float* wk_f = in_w + (long)kD * kD;
    const float* bq = in_b;
    const float* bv = in_b + 2 * kD;

    auto cvt = [&](const float* src, unsigned short* dst, int rows, int scols,
                   int dcols, int coloff) {
        int n8 = rows * (scols / 8);
        cvt_bf16<<<(n8 + 255) / 256, 256, 0, stream>>>(src, dst, scols / 8, dcols, coloff, n8);
    };

    // ---- conversions
    badd_kernel<<<16, 256, 0, stream>>>(b_ih, b_hh, badd);
    cvt(h, h_bf, 512, 1024, 1024, 0);
    cvt(in_w, wq_bf, 1024, 1024, 1024, 0);
    tcvt_wk<<<dim3(32, 16, 2), 256, 0, stream>>>(wk_f, wkT_bf);
    cvt(in_w + 2L * kD * kD, wv_bf, 1024, 1024, 1024, 0);
    cvt(wo, wo_bf, 1024, 1024, 1024, 0);
    cvt(w_ih, wcat, 4096, 2048, 3072, 0);
    cvt(w_hh, wcat, 4096, 1024, 3072, 2048);

    // 1. q_bf = bf16(h @ wq^T + bq)   (q.b_k dropped: softmax-shift-invariant)
    gemm_bf16<<<dim3(8, 8, 1), 256, 0, stream>>>(
        h_bf, 1024, 0, wq_bf, 1024, 0,
        nullptr, 0, 0, q_bf, 1024, 0, bq, 0, 1024);

    // 2. qtl[:, z, :] = q_z @ wkT_z^T   (f32 out)
    gemm_bf16<<<dim3(8, 8, 2), 256, 0, stream>>>(
        q_bf, 1024, 512, wkT_bf, 512, 524288,
        qtl, 2048, 1024, nullptr, 0, 0, nullptr, 0, 512);

    // 3. fused attention (split-4) -> partials
    attn3<<<kB * kSPL, 512, 0, stream>>>(xall, qtl, spart, mlpart);

    // 4. combine partials -> sac_bf (bf16)
    attn_combine<<<kB, 256, 0, stream>>>(spart, mlpart, sac_bf);

    // 5. ctx_bf[:, z*512:] = bf16(s_z @ wv_z^T + bv_z)
    gemm_bf16<<<dim3(4, 8, 2), 256, 0, stream>>>(
        sac_bf, 2048, 1024, wv_bf, 1024, 524288,
        nullptr, 0, 0, ctx_bf, 1024, 512, bv, 512, 1024);

    // 6. acat[:, 0:1024] = bf16(ctx @ wo^T + bo)
    gemm_bf16<<<dim3(8, 8, 1), 256, 0, stream>>>(
        ctx_bf, 1024, 0, wo_bf, 1024, 0,
        nullptr, 0, 0, acat, 3072, 0, bo, 0, 1024);

    // remaining acat columns
    cvt(ext, acat, 512, 1024, 3072, 1024);
    cvt(h,   acat, 512, 1024, 3072, 2048);

    // 7. gates = acat @ wcat^T + (b_ih + b_hh)   (f32 out; aliases attn scratch)
    gemm_bf16<<<dim3(32, 8, 1), 256, 0, stream>>>(
        acat, 3072, 0, wcat, 3072, 0,
        gates, 4096, 0, nullptr, 0, 0, badd, 0, 3072);

    // 8. LSTM cell + LayerNorm
    lstm_ln<<<kB, 256, 0, stream>>>(gates, c, ln_w, ln_b, out0, out1);
}

// Round 6
// 448.849 us; speedup vs baseline: 2.4586x; 1.0041x over previous
//
#include <hip/hip_runtime.h>
#include <math.h>
#include <stdint.h>

constexpr int kD  = 1024;   // model dim
constexpr int kB  = 512;    // batch
constexpr int kN  = 512;    // states per batch
constexpr int kDH = 512;    // head dim (H=2)

using bf16x8 = __attribute__((ext_vector_type(8))) short;
using f32x4v = __attribute__((ext_vector_type(4))) float;
using us8    = __attribute__((ext_vector_type(8))) unsigned short;

__device__ __forceinline__ unsigned short f2bf(float f) {
    uint32_t u = __float_as_uint(f);
    u += 0x7fffu + ((u >> 16) & 1u);     // round-to-nearest-even
    return (unsigned short)(u >> 16);
}

__device__ __forceinline__ float bf2f(unsigned short s) {
    return __uint_as_float((uint32_t)s << 16);
}

__device__ __forceinline__ void async16(const void* g, void* l) {
    __builtin_amdgcn_global_load_lds(
        (const __attribute__((address_space(1))) uint32_t*)g,
        (__attribute__((address_space(3))) uint32_t*)l, 16, 0, 0);
}

// ---------------------------------------------------------------------------
// f32 -> bf16 convert with optional column restride/offset. (round-3 proven)
// ---------------------------------------------------------------------------
__global__ __launch_bounds__(256)
void cvt_bf16(const float* __restrict__ src, unsigned short* __restrict__ dst,
              int scols8, int dcols, int coloff, int n8)
{
    int idx = blockIdx.x * 256 + threadIdx.x;
    if (idx >= n8) return;
    int row = idx / scols8;
    int c = (idx - row * scols8) * 8;
    const float4* s = (const float4*)(src + (long)row * ((long)scols8 * 8) + c);
    float4 v0 = s[0], v1 = s[1];
    us8 o;
    o[0] = f2bf(v0.x); o[1] = f2bf(v0.y); o[2] = f2bf(v0.z); o[3] = f2bf(v0.w);
    o[4] = f2bf(v1.x); o[5] = f2bf(v1.y); o[6] = f2bf(v1.z); o[7] = f2bf(v1.w);
    *(us8*)(dst + (long)row * dcols + coloff + c) = o;
}

// ---------------------------------------------------------------------------
// wk transpose+convert: dst[h][n][k] = wk[h*512+k][n]  (round-3 proven)
// ---------------------------------------------------------------------------
__global__ __launch_bounds__(256)
void tcvt_wk(const float* __restrict__ wk, unsigned short* __restrict__ dst)
{
    __shared__ float t[32][33];
    const int nt = blockIdx.x;     // 0..31 (n tiles)
    const int kt = blockIdx.y;     // 0..15 (k tiles)
    const int hh = blockIdx.z;     // head
    const int tx = threadIdx.x & 31, ty = threadIdx.x >> 5;   // 32 x 8
#pragma unroll
    for (int j = 0; j < 4; ++j)
        t[ty + j * 8][tx] = wk[(long)(hh * 512 + kt * 32 + ty + j * 8) * kD + nt * 32 + tx];
    __syncthreads();
#pragma unroll
    for (int j = 0; j < 4; ++j) {
        int n = nt * 32 + ty + j * 8;
        int k = kt * 32 + tx;
        dst[(long)hh * 524288 + (long)n * 512 + k] = f2bf(t[tx][ty + j * 8]);
    }
}

__global__ __launch_bounds__(256)
void badd_kernel(const float* __restrict__ a, const float* __restrict__ b,
                 float* __restrict__ o)
{
    int i = blockIdx.x * 256 + threadIdx.x;
    if (i < 4096) o[i] = a[i] + b[i];
}

// ---------------------------------------------------------------------------
// bf16 MFMA GEMM, NT (round-3 proven). 64x128 tile, BK=32, 256 threads.
// ---------------------------------------------------------------------------
__global__ __launch_bounds__(256)
void gemm_bf16(const unsigned short* __restrict__ A, int lda, long sAz,
               const unsigned short* __restrict__ B, int ldb, long sBz,
               float* __restrict__ Cf, int ldcf, long sCfz,
               unsigned short* __restrict__ Cb, int ldcb, long sCbz,
               const float* __restrict__ bias, long sbz, int K)
{
    __shared__ short As[4][64][8];
    __shared__ short Bs[4][128][8];
    A += (long)blockIdx.z * sAz;
    B += (long)blockIdx.z * sBz;

    const int tid = threadIdx.x;
    const int l = tid & 63, w = tid >> 6;
    const int wr = w >> 1, wc = w & 1;
    const int bm = blockIdx.y * 64, bn = blockIdx.x * 128;

    f32x4v acc[2][4] = {};

    for (int k0 = 0; k0 < K; k0 += 32) {
        __syncthreads();
        {
            int ks = tid >> 6, r = tid & 63;
            async16(A + (long)(bm + r) * lda + k0 + ks * 8, (short*)As + (long)tid * 8);
        }
#pragma unroll
        for (int j = 0; j < 2; ++j) {
            int ca = j * 256 + tid;
            int ks = ca >> 7, r = ca & 127;
            async16(B + (long)(bn + r) * ldb + k0 + ks * 8, (short*)Bs + (long)ca * 8);
        }
        __syncthreads();   // compiler drains vmcnt before barrier (m97 pattern)

        const int ks = l >> 4, rr = l & 15;
        bf16x8 a[2], b[4];
#pragma unroll
        for (int t = 0; t < 2; ++t)
            a[t] = *(const bf16x8*)&As[ks][wr * 32 + t * 16 + rr][0];
#pragma unroll
        for (int t = 0; t < 4; ++t)
            b[t] = *(const bf16x8*)&Bs[ks][wc * 64 + t * 16 + rr][0];
#pragma unroll
        for (int mt = 0; mt < 2; ++mt)
#pragma unroll
            for (int nt = 0; nt < 4; ++nt)
                acc[mt][nt] = __builtin_amdgcn_mfma_f32_16x16x32_bf16(
                    a[mt], b[nt], acc[mt][nt], 0, 0, 0);
    }

    const int rr = l & 15, rg = l >> 4;
#pragma unroll
    for (int mt = 0; mt < 2; ++mt) {
#pragma unroll
        for (int nt = 0; nt < 4; ++nt) {
            const int n = bn + wc * 64 + nt * 16 + rr;
            float bb = bias ? bias[(long)blockIdx.z * sbz + n] : 0.f;
#pragma unroll
            for (int r = 0; r < 4; ++r) {
                const int m = bm + wr * 32 + mt * 16 + rg * 4 + r;
                float val = acc[mt][nt][r] + bb;
                if (Cf) Cf[(long)blockIdx.z * sCfz + (long)m * ldcf + n] = val;
                if (Cb) Cb[(long)blockIdx.z * sCbz + (long)m * ldcb + n] = f2bf(val);
            }
        }
    }
}

// ---------------------------------------------------------------------------
// attn6: barrier-free, LDS-free streaming attention.
// One block per b (512 threads = 8 waves); wave w owns rows [w*64, w*64+64)
// as an INDEPENDENT online-softmax unit (defer-max, THR=8). Lane l owns
// d in [l*16, l*16+16): the same 16 x-registers feed the score dot-product
// (6-step shfl_xor reduce) and the weighted state accumulation.
// Latency hiding is pure TLP (16 waves/CU, ~64KB/CU in flight).
// Per-wave unnormalized partials out (bf16) + (m,l) f32.
// q.b_k term omitted (softmax-shift-invariant).
// ---------------------------------------------------------------------------
__global__ __launch_bounds__(512, 4)
void attn6(const float* __restrict__ xall,        // [B][N][D] f32
           const float* __restrict__ qt,          // [B][2][D] f32
           unsigned short* __restrict__ spart_bf, // [B][8][2][1024] bf16
           float* __restrict__ mlpart)            // [B][8][2][2] f32
{
    const int b = blockIdx.x;
    const int tid = threadIdx.x;
    const int w = tid >> 6, l = tid & 63;
    const float scale = 0.044194173824159216f;    // 1/sqrt(512)

    // q-tilde: lane l holds elements [l*16, l*16+16) of each head
    float qa[16], qb[16];
    {
        const float* qp = qt + (long)b * 2048 + l * 16;
#pragma unroll
        for (int j = 0; j < 4; ++j) {
            float4 v0 = *(const float4*)(qp + j * 4);
            float4 v1 = *(const float4*)(qp + 1024 + j * 4);
            qa[j*4+0] = v0.x; qa[j*4+1] = v0.y; qa[j*4+2] = v0.z; qa[j*4+3] = v0.w;
            qb[j*4+0] = v1.x; qb[j*4+1] = v1.y; qb[j*4+2] = v1.z; qb[j*4+3] = v1.w;
        }
    }

    float m0 = -1e30f, l0 = 0.f, m1 = -1e30f, l1 = 0.f;
    float sa[16] = {}, sb[16] = {};

    const float* xr = xall + ((long)b * kN + w * 64) * kD + l * 16;

    for (int r = 0; r < 64; ++r) {
        float xv[16];
#pragma unroll
        for (int j = 0; j < 4; ++j) {
            float4 v = *(const float4*)(xr + j * 4);
            xv[j*4+0] = v.x; xv[j*4+1] = v.y; xv[j*4+2] = v.z; xv[j*4+3] = v.w;
        }
        xr += kD;

        float d0 = 0.f, d1 = 0.f;
#pragma unroll
        for (int j = 0; j < 16; ++j) { d0 += xv[j] * qa[j]; d1 += xv[j] * qb[j]; }
#pragma unroll
        for (int mm = 32; mm >= 1; mm >>= 1) {
            d0 += __shfl_xor(d0, mm);
            d1 += __shfl_xor(d1, mm);
        }
        float v0 = d0 * scale, v1 = d1 * scale;   // wave-uniform

        if (v0 > m0 + 8.f) {                       // defer-max (T13), uniform branch
            float rsc = __expf(m0 - v0);           // first row: exp(-inf)=0, clean init
            l0 *= rsc;
#pragma unroll
            for (int j = 0; j < 16; ++j) sa[j] *= rsc;
            m0 = v0;
        }
        float p0 = __expf(v0 - m0);                // bounded by e^8
        l0 += p0;

        if (v1 > m1 + 8.f) {
            float rsc = __expf(m1 - v1);
            l1 *= rsc;
#pragma unroll
            for (int j = 0; j < 16; ++j) sb[j] *= rsc;
            m1 = v1;
        }
        float p1 = __expf(v1 - m1);
        l1 += p1;

#pragma unroll
        for (int j = 0; j < 16; ++j) {
            sa[j] += p0 * xv[j];
            sb[j] += p1 * xv[j];
        }
    }

    // epilogue: bf16 partials
    unsigned short* sp0 = spart_bf + (((long)b * 8 + w) * 2 + 0) * 1024 + l * 16;
    unsigned short* sp1 = spart_bf + (((long)b * 8 + w) * 2 + 1) * 1024 + l * 16;
    us8 o0, o1;
#pragma unroll
    for (int j = 0; j < 8; ++j) { o0[j] = f2bf(sa[j]); o1[j] = f2bf(sa[j + 8]); }
    *(us8*)(sp0) = o0; *(us8*)(sp0 + 8) = o1;
#pragma unroll
    for (int j = 0; j < 8; ++j) { o0[j] = f2bf(sb[j]); o1[j] = f2bf(sb[j + 8]); }
    *(us8*)(sp1) = o0; *(us8*)(sp1 + 8) = o1;

    if (l == 0) {
        float* mlp = mlpart + (((long)b * 8 + w) * 2) * 2;
        mlp[0] = m0; mlp[1] = l0; mlp[2] = m1; mlp[3] = l1;
    }
}

// ---------------------------------------------------------------------------
// Combine 8 per-wave partials -> normalized sums (bf16, GEMM-5 A layout)
// ---------------------------------------------------------------------------
__global__ __launch_bounds__(256)
void attn_combine8(const unsigned short* __restrict__ spart_bf,
                   const float* __restrict__ mlpart,
                   unsigned short* __restrict__ sac_bf)
{
    const int b = blockIdx.x;
    const int tid = threadIdx.x;
    const int h = tid >> 7, d0 = (tid & 127) * 8;

    float m[8], lv[8];
#pragma unroll
    for (int c = 0; c < 8; ++c) {
        const float* mlp = mlpart + (((long)b * 8 + c) * 2 + h) * 2;
        m[c] = mlp[0]; lv[c] = mlp[1];
    }
    float ms = m[0];
#pragma unroll
    for (int c = 1; c < 8; ++c) ms = fmaxf(ms, m[c]);
    float wgt[8], L = 0.f;
#pragma unroll
    for (int c = 0; c < 8; ++c) { wgt[c] = __expf(m[c] - ms); L += wgt[c] * lv[c]; }
    const float inv = 1.0f / L;

    float acc[8] = {};
#pragma unroll
    for (int c = 0; c < 8; ++c) {
        us8 sv = *(const us8*)(spart_bf + (((long)b * 8 + c) * 2 + h) * 1024 + d0);
#pragma unroll
        for (int j = 0; j < 8; ++j)
            acc[j] += wgt[c] * bf2f(sv[j]);
    }
    us8 o;
#pragma unroll
    for (int j = 0; j < 8; ++j) o[j] = f2bf(acc[j] * inv);
    *(us8*)(sac_bf + (long)b * 2048 + h * kD + d0) = o;
}

// ---------------------------------------------------------------------------
// Fused LSTM cell + LayerNorm (round-3 proven).
// ---------------------------------------------------------------------------
__device__ __forceinline__ float sigm(float x) { return 1.0f / (1.0f + __expf(-x)); }

__global__ __launch_bounds__(256)
void lstm_ln(const float* __restrict__ gates, const float* __restrict__ cin,
             const float* __restrict__ ln_w, const float* __restrict__ ln_b,
             float* __restrict__ out0, float* __restrict__ out1)
{
    __shared__ float red[2][4];
    __shared__ float stats[2];

    const int b = blockIdx.x;
    const int tid = threadIdx.x;
    const int d4 = tid * 4;
    const float* g = gates + (long)b * 4096;

    float4 gi = *(const float4*)(g + d4);
    float4 gf = *(const float4*)(g + 1024 + d4);
    float4 gg = *(const float4*)(g + 2048 + d4);
    float4 go = *(const float4*)(g + 3072 + d4);
    float4 cv = *(const float4*)(cin + (long)b * kD + d4);

    float iv[4] = {gi.x, gi.y, gi.z, gi.w};
    float fv[4] = {gf.x, gf.y, gf.z, gf.w};
    float gv[4] = {gg.x, gg.y, gg.z, gg.w};
    float ov[4] = {go.x, go.y, go.z, go.w};
    float cc[4] = {cv.x, cv.y, cv.z, cv.w};

    float nc[4], nh[4];
#pragma unroll
    for (int u = 0; u < 4; ++u) {
        nc[u] = sigm(fv[u]) * cc[u] + sigm(iv[u]) * tanhf(gv[u]);
        nh[u] = sigm(ov[u]) * tanhf(nc[u]);
    }
    *(float4*)(out1 + (long)b * kD + d4) = make_float4(nc[0], nc[1], nc[2], nc[3]);

    float sum = nh[0] + nh[1] + nh[2] + nh[3];
    float ss  = nh[0]*nh[0] + nh[1]*nh[1] + nh[2]*nh[2] + nh[3]*nh[3];
#pragma unroll
    for (int m = 32; m >= 1; m >>= 1) {
        sum += __shfl_xor(sum, m);
        ss  += __shfl_xor(ss, m);
    }
    const int wave = tid >> 6, lane = tid & 63;
    if (lane == 0) { red[0][wave] = sum; red[1][wave] = ss; }
    __syncthreads();
    if (tid == 0) {
        float s = red[0][0] + red[0][1] + red[0][2] + red[0][3];
        float q = red[1][0] + red[1][1] + red[1][2] + red[1][3];
        float mu = s / (float)kD;
        float var = q / (float)kD - mu * mu;
        stats[0] = mu;
        stats[1] = rsqrtf(var + 1e-5f);
    }
    __syncthreads();
    const float mu = stats[0], rstd = stats[1];
    float4 lw = *(const float4*)(ln_w + d4);
    float4 lb = *(const float4*)(ln_b + d4);
    float lwv[4] = {lw.x, lw.y, lw.z, lw.w};
    float lbv[4] = {lb.x, lb.y, lb.z, lb.w};
    float o[4];
#pragma unroll
    for (int u = 0; u < 4; ++u)
        o[u] = (nh[u] - mu) * rstd * lwv[u] + lbv[u];
    *(float4*)(out0 + (long)b * kD + d4) = make_float4(o[0], o[1], o[2], o[3]);
}

// ---------------------------------------------------------------------------
extern "C" void kernel_launch(void* const* d_in, const int* in_sizes, int n_in,
                              void* d_out, int out_size, void* d_ws, size_t ws_size,
                              hipStream_t stream)
{
    (void)in_sizes; (void)n_in; (void)out_size;

    const float* h    = (const float*)d_in[0];
    const float* c    = (const float*)d_in[1];
    const float* xall = (const float*)d_in[2];
    const float* ext  = (const float*)d_in[3];
    const float* in_w = (const float*)d_in[4];
    const float* in_b = (const float*)d_in[5];
    const float* wo   = (const float*)d_in[6];
    const float* bo   = (const float*)d_in[7];
    const float* w_ih = (const float*)d_in[8];
    const float* b_ih = (const float*)d_in[9];
    const float* w_hh = (const float*)d_in[10];
    const float* b_hh = (const float*)d_in[11];
    const float* ln_w = (const float*)d_in[12];
    const float* ln_b = (const float*)d_in[13];

    float* out0 = (float*)d_out;              // LN(new_h) [512x1024]
    float* out1 = out0 + (long)kB * kD;       // new_c     [512x1024]

    // ---- workspace layout (bytes; 16B-aligned chunks)
    char* p = (char*)d_ws;
    const size_t need = 63062016ull;
    if (ws_size < need) return;

    float*          badd   = (float*)p;          p += 16384;     // [4096]
    unsigned short* h_bf   = (unsigned short*)p; p += 1048576;   // [512][1024]
    unsigned short* wq_bf  = (unsigned short*)p; p += 2097152;   // [1024][1024]
    unsigned short* wkT_bf = (unsigned short*)p; p += 2097152;   // [2][1024][512]
    unsigned short* wv_bf  = (unsigned short*)p; p += 2097152;   // [1024][1024]
    unsigned short* wo_bf  = (unsigned short*)p; p += 2097152;   // [1024][1024]
    unsigned short* q_bf   = (unsigned short*)p; p += 1048576;   // [512][1024]
    unsigned short* sac_bf = (unsigned short*)p; p += 2097152;   // [512][2048]
    unsigned short* ctx_bf = (unsigned short*)p; p += 1048576;   // [512][1024]
    unsigned short* acat   = (unsigned short*)p; p += 3145728;   // [512][3072]
    unsigned short* wcat   = (unsigned short*)p; p += 25165824;  // [4096][3072]
    // overlay region: {qtl, spart, mlpart} (attention) / {gates} (after combine)
    char* ov = p;
    float*          qtl      = (float*)ov;                       // [512][2][1024] f32
    unsigned short* spart_bf = (unsigned short*)(ov + 4194304);  // [512][8][2][1024] bf16
    float*          mlpart   = (float*)(ov + 4194304 + 16777216);// [512][8][2][2]
    float*          gates    = (float*)ov;                       // [512][4096] (aliases, later)

    const float* wk_f = in_w + (long)kD * kD;
    const float* bq = in_b;
    const float* bv = in_b + 2 * kD;

    auto cvt = [&](const float* src, unsigned short* dst, int rows, int scols,
                   int dcols, int coloff) {
        int n8 = rows * (scols / 8);
        cvt_bf16<<<(n8 + 255) / 256, 256, 0, stream>>>(src, dst, scols / 8, dcols, coloff, n8);
    };

    // ---- conversions (round-3 proven forms)
    badd_kernel<<<16, 256, 0, stream>>>(b_ih, b_hh, badd);
    cvt(h, h_bf, 512, 1024, 1024, 0);
    cvt(in_w, wq_bf, 1024, 1024, 1024, 0);
    tcvt_wk<<<dim3(32, 16, 2), 256, 0, stream>>>(wk_f, wkT_bf);
    cvt(in_w + 2L * kD * kD, wv_bf, 1024, 1024, 1024, 0);
    cvt(wo, wo_bf, 1024, 1024, 1024, 0);
    cvt(w_ih, wcat, 4096, 2048, 3072, 0);
    cvt(w_hh, wcat, 4096, 1024, 3072, 2048);

    // 1. q_bf = bf16(h @ wq^T + bq)   (q.b_k dropped: softmax-shift-invariant)
    gemm_bf16<<<dim3(8, 8, 1), 256, 0, stream>>>(
        h_bf, 1024, 0, wq_bf, 1024, 0,
        nullptr, 0, 0, q_bf, 1024, 0, bq, 0, 1024);

    // 2. qtl[:, z, :] = q_z @ wkT_z^T   (f32 out)
    gemm_bf16<<<dim3(8, 8, 2), 256, 0, stream>>>(
        q_bf, 1024, 512, wkT_bf, 512, 524288,
        qtl, 2048, 1024, nullptr, 0, 0, nullptr, 0, 512);

    // 3. barrier-free streaming attention -> per-wave partials
    attn6<<<kB, 512, 0, stream>>>(xall, qtl, spart_bf, mlpart);

    // 4. combine 8 partials -> sac_bf (bf16)
    attn_combine8<<<kB, 256, 0, stream>>>(spart_bf, mlpart, sac_bf);

    // 5. ctx_bf[:, z*512:] = bf16(s_z @ wv_z^T + bv_z)
    gemm_bf16<<<dim3(4, 8, 2), 256, 0, stream>>>(
        sac_bf, 2048, 1024, wv_bf, 1024, 524288,
        nullptr, 0, 0, ctx_bf, 1024, 512, bv, 512, 1024);

    // 6. acat[:, 0:1024] = bf16(ctx @ wo^T + bo)
    gemm_bf16<<<dim3(8, 8, 1), 256, 0, stream>>>(
        ctx_bf, 1024, 0, wo_bf, 1024, 0,
        nullptr, 0, 0, acat, 3072, 0, bo, 0, 1024);

    // remaining acat columns
    cvt(ext, acat, 512, 1024, 3072, 1024);
    cvt(h,   acat, 512, 1024, 3072, 2048);

    // 7. gates = acat @ wcat^T + (b_ih + b_hh)   (f32 out; aliases attn scratch)
    gemm_bf16<<<dim3(32, 8, 1), 256, 0, stream>>>(
        acat, 3072, 0, wcat, 3072, 0,
        gates, 4096, 0, nullptr, 0, 0, badd, 0, 3072);

    // 8. LSTM cell + LayerNorm
    lstm_ln<<<kB, 256, 0, stream>>>(gates, c, ln_w, ln_b, out0, out1);
}

// Round 7
// 444.968 us; speedup vs baseline: 2.4801x; 1.0087x over previous
//
#include <hip/hip_runtime.h>
#include <math.h>
#include <stdint.h>

constexpr int kD  = 1024;   // model dim
constexpr int kB  = 512;    // batch
constexpr int kN  = 512;    // states per batch
constexpr int kDH = 512;    // head dim (H=2)

using bf16x8 = __attribute__((ext_vector_type(8))) short;
using f32x4v = __attribute__((ext_vector_type(4))) float;
using us8    = __attribute__((ext_vector_type(8))) unsigned short;
using us4    = __attribute__((ext_vector_type(4))) unsigned short;

__device__ __forceinline__ unsigned short f2bf(float f) {
    uint32_t u = __float_as_uint(f);
    u += 0x7fffu + ((u >> 16) & 1u);     // round-to-nearest-even
    return (unsigned short)(u >> 16);
}

__device__ __forceinline__ float bf2f(unsigned short s) {
    return __uint_as_float((uint32_t)s << 16);
}

__device__ __forceinline__ void async16(const void* g, void* l) {
    __builtin_amdgcn_global_load_lds(
        (const __attribute__((address_space(1))) uint32_t*)g,
        (__attribute__((address_space(3))) uint32_t*)l, 16, 0, 0);
}

// ---------------------------------------------------------------------------
// f32 -> bf16 convert with optional column restride/offset. (round-3 proven)
// ---------------------------------------------------------------------------
__global__ __launch_bounds__(256)
void cvt_bf16(const float* __restrict__ src, unsigned short* __restrict__ dst,
              int scols8, int dcols, int coloff, int n8)
{
    int idx = blockIdx.x * 256 + threadIdx.x;
    if (idx >= n8) return;
    int row = idx / scols8;
    int c = (idx - row * scols8) * 8;
    const float4* s = (const float4*)(src + (long)row * ((long)scols8 * 8) + c);
    float4 v0 = s[0], v1 = s[1];
    us8 o;
    o[0] = f2bf(v0.x); o[1] = f2bf(v0.y); o[2] = f2bf(v0.z); o[3] = f2bf(v0.w);
    o[4] = f2bf(v1.x); o[5] = f2bf(v1.y); o[6] = f2bf(v1.z); o[7] = f2bf(v1.w);
    *(us8*)(dst + (long)row * dcols + coloff + c) = o;
}

// ---------------------------------------------------------------------------
// wk transpose+convert with SCALE FOLDED IN:
// dst[h][n][k] = bf16( wk[h*512+k][n] * 1/sqrt(512) )
// ---------------------------------------------------------------------------
__global__ __launch_bounds__(256)
void tcvt_wk(const float* __restrict__ wk, unsigned short* __restrict__ dst)
{
    __shared__ float t[32][33];
    const int nt = blockIdx.x;     // 0..31 (n tiles)
    const int kt = blockIdx.y;     // 0..15 (k tiles)
    const int hh = blockIdx.z;     // head
    const int tx = threadIdx.x & 31, ty = threadIdx.x >> 5;   // 32 x 8
    const float scale = 0.044194173824159216f;   // 1/sqrt(512)
#pragma unroll
    for (int j = 0; j < 4; ++j)
        t[ty + j * 8][tx] = wk[(long)(hh * 512 + kt * 32 + ty + j * 8) * kD + nt * 32 + tx];
    __syncthreads();
#pragma unroll
    for (int j = 0; j < 4; ++j) {
        int n = nt * 32 + ty + j * 8;
        int k = kt * 32 + tx;
        dst[(long)hh * 524288 + (long)n * 512 + k] = f2bf(t[tx][ty + j * 8] * scale);
    }
}

__global__ __launch_bounds__(256)
void badd_kernel(const float* __restrict__ a, const float* __restrict__ b,
                 float* __restrict__ o)
{
    int i = blockIdx.x * 256 + threadIdx.x;
    if (i < 4096) o[i] = a[i] + b[i];
}

// ---------------------------------------------------------------------------
// bf16 MFMA GEMM, NT (round-3 proven). 64x128 tile, BK=32, 256 threads.
// ---------------------------------------------------------------------------
__global__ __launch_bounds__(256)
void gemm_bf16(const unsigned short* __restrict__ A, int lda, long sAz,
               const unsigned short* __restrict__ B, int ldb, long sBz,
               float* __restrict__ Cf, int ldcf, long sCfz,
               unsigned short* __restrict__ Cb, int ldcb, long sCbz,
               const float* __restrict__ bias, long sbz, int K)
{
    __shared__ short As[4][64][8];
    __shared__ short Bs[4][128][8];
    A += (long)blockIdx.z * sAz;
    B += (long)blockIdx.z * sBz;

    const int tid = threadIdx.x;
    const int l = tid & 63, w = tid >> 6;
    const int wr = w >> 1, wc = w & 1;
    const int bm = blockIdx.y * 64, bn = blockIdx.x * 128;

    f32x4v acc[2][4] = {};

    for (int k0 = 0; k0 < K; k0 += 32) {
        __syncthreads();
        {
            int ks = tid >> 6, r = tid & 63;
            async16(A + (long)(bm + r) * lda + k0 + ks * 8, (short*)As + (long)tid * 8);
        }
#pragma unroll
        for (int j = 0; j < 2; ++j) {
            int ca = j * 256 + tid;
            int ks = ca >> 7, r = ca & 127;
            async16(B + (long)(bn + r) * ldb + k0 + ks * 8, (short*)Bs + (long)ca * 8);
        }
        __syncthreads();   // compiler drains vmcnt before barrier (m97 pattern)

        const int ks = l >> 4, rr = l & 15;
        bf16x8 a[2], b[4];
#pragma unroll
        for (int t = 0; t < 2; ++t)
            a[t] = *(const bf16x8*)&As[ks][wr * 32 + t * 16 + rr][0];
#pragma unroll
        for (int t = 0; t < 4; ++t)
            b[t] = *(const bf16x8*)&Bs[ks][wc * 64 + t * 16 + rr][0];
#pragma unroll
        for (int mt = 0; mt < 2; ++mt)
#pragma unroll
            for (int nt = 0; nt < 4; ++nt)
                acc[mt][nt] = __builtin_amdgcn_mfma_f32_16x16x32_bf16(
                    a[mt], b[nt], acc[mt][nt], 0, 0, 0);
    }

    const int rr = l & 15, rg = l >> 4;
#pragma unroll
    for (int mt = 0; mt < 2; ++mt) {
#pragma unroll
        for (int nt = 0; nt < 4; ++nt) {
            const int n = bn + wc * 64 + nt * 16 + rr;
            float bb = bias ? bias[(long)blockIdx.z * sbz + n] : 0.f;
#pragma unroll
            for (int r = 0; r < 4; ++r) {
                const int m = bm + wr * 32 + mt * 16 + rg * 4 + r;
                float val = acc[mt][nt][r] + bb;
                if (Cf) Cf[(long)blockIdx.z * sCfz + (long)m * ldcf + n] = val;
                if (Cb) Cb[(long)blockIdx.z * sCbz + (long)m * ldcb + n] = f2bf(val);
            }
        }
    }
}

// ---------------------------------------------------------------------------
// attn7: barrier-free, LDS-free streaming attention with COALESCED loads.
// One block per b (512 threads = 8 waves); wave w owns rows [w*64, w*64+64)
// as an independent online-softmax unit (defer-max, THR=8).
// Lane l owns elements e(q,s) = q*256 + l*4 + s (q,s in 0..3): each of the
// 4 float4 loads per row is lane-CONTIGUOUS over a 1KB quarter (8 cache
// lines/instr vs 32 for the old l*16 stride pattern). The same 16 registers
// feed the score dot (4-way split chains + 6-step shfl_xor) and the
// weighted accumulation. Scale is pre-folded into wkT.
// ---------------------------------------------------------------------------
__global__ __launch_bounds__(512, 4)
void attn7(const float* __restrict__ xall,        // [B][N][D] f32
           const float* __restrict__ qt,          // [B][2][D] f32 (pre-scaled)
           unsigned short* __restrict__ spart_bf, // [B][8][2][1024] bf16
           float* __restrict__ mlpart)            // [B][8][2][2] f32
{
    const int b = blockIdx.x;
    const int tid = threadIdx.x;
    const int w = tid >> 6, l = tid & 63;

    // q-tilde: lane l holds elements q*256 + l*4 + s of each head
    float qa[16], qb[16];
    {
        const float* qp = qt + (long)b * 2048 + l * 4;
#pragma unroll
        for (int q = 0; q < 4; ++q) {
            float4 v0 = *(const float4*)(qp + q * 256);
            float4 v1 = *(const float4*)(qp + 1024 + q * 256);
            qa[q*4+0] = v0.x; qa[q*4+1] = v0.y; qa[q*4+2] = v0.z; qa[q*4+3] = v0.w;
            qb[q*4+0] = v1.x; qb[q*4+1] = v1.y; qb[q*4+2] = v1.z; qb[q*4+3] = v1.w;
        }
    }

    float m0 = -1e30f, l0 = 0.f, m1 = -1e30f, l1 = 0.f;
    float sa[16] = {}, sb[16] = {};

    const float* xr = xall + ((long)b * kN + w * 64) * kD + l * 4;

    for (int r = 0; r < 64; ++r) {
        float xv[16];
#pragma unroll
        for (int q = 0; q < 4; ++q) {
            float4 v = *(const float4*)(xr + q * 256);
            xv[q*4+0] = v.x; xv[q*4+1] = v.y; xv[q*4+2] = v.z; xv[q*4+3] = v.w;
        }
        xr += kD;

        // 4-way split dot chains, both heads
        float c0=0.f,c1=0.f,c2=0.f,c3=0.f, e0=0.f,e1=0.f,e2=0.f,e3=0.f;
#pragma unroll
        for (int q = 0; q < 4; ++q) {
            c0 += xv[q*4+0]*qa[q*4+0]; c1 += xv[q*4+1]*qa[q*4+1];
            c2 += xv[q*4+2]*qa[q*4+2]; c3 += xv[q*4+3]*qa[q*4+3];
            e0 += xv[q*4+0]*qb[q*4+0]; e1 += xv[q*4+1]*qb[q*4+1];
            e2 += xv[q*4+2]*qb[q*4+2]; e3 += xv[q*4+3]*qb[q*4+3];
        }
        float d0 = (c0 + c1) + (c2 + c3);
        float d1 = (e0 + e1) + (e2 + e3);
#pragma unroll
        for (int mm = 32; mm >= 1; mm >>= 1) {
            d0 += __shfl_xor(d0, mm);
            d1 += __shfl_xor(d1, mm);
        }
        // (scale already folded into wkT -> d0/d1 are final logits)

        if (d0 > m0 + 8.f) {                       // defer-max (T13), uniform
            float rsc = __expf(m0 - d0);           // first row: exp(-inf)=0
            l0 *= rsc;
#pragma unroll
            for (int j = 0; j < 16; ++j) sa[j] *= rsc;
            m0 = d0;
        }
        float p0 = __expf(d0 - m0);                // bounded by e^8
        l0 += p0;

        if (d1 > m1 + 8.f) {
            float rsc = __expf(m1 - d1);
            l1 *= rsc;
#pragma unroll
            for (int j = 0; j < 16; ++j) sb[j] *= rsc;
            m1 = d1;
        }
        float p1 = __expf(d1 - m1);
        l1 += p1;

#pragma unroll
        for (int j = 0; j < 16; ++j) {
            sa[j] += p0 * xv[j];
            sb[j] += p1 * xv[j];
        }
    }

    // epilogue: bf16 partials at canonical positions e = q*256 + l*4 + s
    unsigned short* sp0 = spart_bf + (((long)b * 8 + w) * 2 + 0) * 1024 + l * 4;
    unsigned short* sp1 = spart_bf + (((long)b * 8 + w) * 2 + 1) * 1024 + l * 4;
#pragma unroll
    for (int q = 0; q < 4; ++q) {
        us4 o0, o1;
        o0[0] = f2bf(sa[q*4+0]); o0[1] = f2bf(sa[q*4+1]);
        o0[2] = f2bf(sa[q*4+2]); o0[3] = f2bf(sa[q*4+3]);
        o1[0] = f2bf(sb[q*4+0]); o1[1] = f2bf(sb[q*4+1]);
        o1[2] = f2bf(sb[q*4+2]); o1[3] = f2bf(sb[q*4+3]);
        *(us4*)(sp0 + q * 256) = o0;
        *(us4*)(sp1 + q * 256) = o1;
    }

    if (l == 0) {
        float* mlp = mlpart + (((long)b * 8 + w) * 2) * 2;
        mlp[0] = m0; mlp[1] = l0; mlp[2] = m1; mlp[3] = l1;
    }
}

// ---------------------------------------------------------------------------
// Combine 8 per-wave partials -> normalized sums (bf16, GEMM-5 A layout)
// ---------------------------------------------------------------------------
__global__ __launch_bounds__(256)
void attn_combine8(const unsigned short* __restrict__ spart_bf,
                   const float* __restrict__ mlpart,
                   unsigned short* __restrict__ sac_bf)
{
    const int b = blockIdx.x;
    const int tid = threadIdx.x;
    const int h = tid >> 7, d0 = (tid & 127) * 8;

    float m[8], lv[8];
#pragma unroll
    for (int c = 0; c < 8; ++c) {
        const float* mlp = mlpart + (((long)b * 8 + c) * 2 + h) * 2;
        m[c] = mlp[0]; lv[c] = mlp[1];
    }
    float ms = m[0];
#pragma unroll
    for (int c = 1; c < 8; ++c) ms = fmaxf(ms, m[c]);
    float wgt[8], L = 0.f;
#pragma unroll
    for (int c = 0; c < 8; ++c) { wgt[c] = __expf(m[c] - ms); L += wgt[c] * lv[c]; }
    const float inv = 1.0f / L;

    float acc[8] = {};
#pragma unroll
    for (int c = 0; c < 8; ++c) {
        us8 sv = *(const us8*)(spart_bf + (((long)b * 8 + c) * 2 + h) * 1024 + d0);
#pragma unroll
        for (int j = 0; j < 8; ++j)
            acc[j] += wgt[c] * bf2f(sv[j]);
    }
    us8 o;
#pragma unroll
    for (int j = 0; j < 8; ++j) o[j] = f2bf(acc[j] * inv);
    *(us8*)(sac_bf + (long)b * 2048 + h * kD + d0) = o;
}

// ---------------------------------------------------------------------------
// Fused LSTM cell + LayerNorm (round-3 proven).
// ---------------------------------------------------------------------------
__device__ __forceinline__ float sigm(float x) { return 1.0f / (1.0f + __expf(-x)); }

__global__ __launch_bounds__(256)
void lstm_ln(const float* __restrict__ gates, const float* __restrict__ cin,
             const float* __restrict__ ln_w, const float* __restrict__ ln_b,
             float* __restrict__ out0, float* __restrict__ out1)
{
    __shared__ float red[2][4];
    __shared__ float stats[2];

    const int b = blockIdx.x;
    const int tid = threadIdx.x;
    const int d4 = tid * 4;
    const float* g = gates + (long)b * 4096;

    float4 gi = *(const float4*)(g + d4);
    float4 gf = *(const float4*)(g + 1024 + d4);
    float4 gg = *(const float4*)(g + 2048 + d4);
    float4 go = *(const float4*)(g + 3072 + d4);
    float4 cv = *(const float4*)(cin + (long)b * kD + d4);

    float iv[4] = {gi.x, gi.y, gi.z, gi.w};
    float fv[4] = {gf.x, gf.y, gf.z, gf.w};
    float gv[4] = {gg.x, gg.y, gg.z, gg.w};
    float ov[4] = {go.x, go.y, go.z, go.w};
    float cc[4] = {cv.x, cv.y, cv.z, cv.w};

    float nc[4], nh[4];
#pragma unroll
    for (int u = 0; u < 4; ++u) {
        nc[u] = sigm(fv[u]) * cc[u] + sigm(iv[u]) * tanhf(gv[u]);
        nh[u] = sigm(ov[u]) * tanhf(nc[u]);
    }
    *(float4*)(out1 + (long)b * kD + d4) = make_float4(nc[0], nc[1], nc[2], nc[3]);

    float sum = nh[0] + nh[1] + nh[2] + nh[3];
    float ss  = nh[0]*nh[0] + nh[1]*nh[1] + nh[2]*nh[2] + nh[3]*nh[3];
#pragma unroll
    for (int m = 32; m >= 1; m >>= 1) {
        sum += __shfl_xor(sum, m);
        ss  += __shfl_xor(ss, m);
    }
    const int wave = tid >> 6, lane = tid & 63;
    if (lane == 0) { red[0][wave] = sum; red[1][wave] = ss; }
    __syncthreads();
    if (tid == 0) {
        float s = red[0][0] + red[0][1] + red[0][2] + red[0][3];
        float q = red[1][0] + red[1][1] + red[1][2] + red[1][3];
        float mu = s / (float)kD;
        float var = q / (float)kD - mu * mu;
        stats[0] = mu;
        stats[1] = rsqrtf(var + 1e-5f);
    }
    __syncthreads();
    const float mu = stats[0], rstd = stats[1];
    float4 lw = *(const float4*)(ln_w + d4);
    float4 lb = *(const float4*)(ln_b + d4);
    float lwv[4] = {lw.x, lw.y, lw.z, lw.w};
    float lbv[4] = {lb.x, lb.y, lb.z, lb.w};
    float o[4];
#pragma unroll
    for (int u = 0; u < 4; ++u)
        o[u] = (nh[u] - mu) * rstd * lwv[u] + lbv[u];
    *(float4*)(out0 + (long)b * kD + d4) = make_float4(o[0], o[1], o[2], o[3]);
}

// ---------------------------------------------------------------------------
extern "C" void kernel_launch(void* const* d_in, const int* in_sizes, int n_in,
                              void* d_out, int out_size, void* d_ws, size_t ws_size,
                              hipStream_t stream)
{
    (void)in_sizes; (void)n_in; (void)out_size;

    const float* h    = (const float*)d_in[0];
    const float* c    = (const float*)d_in[1];
    const float* xall = (const float*)d_in[2];
    const float* ext  = (const float*)d_in[3];
    const float* in_w = (const float*)d_in[4];
    const float* in_b = (const float*)d_in[5];
    const float* wo   = (const float*)d_in[6];
    const float* bo   = (const float*)d_in[7];
    const float* w_ih = (const float*)d_in[8];
    const float* b_ih = (const float*)d_in[9];
    const float* w_hh = (const float*)d_in[10];
    const float* b_hh = (const float*)d_in[11];
    const float* ln_w = (const float*)d_in[12];
    const float* ln_b = (const float*)d_in[13];

    float* out0 = (float*)d_out;              // LN(new_h) [512x1024]
    float* out1 = out0 + (long)kB * kD;       // new_c     [512x1024]

    // ---- workspace layout (bytes; 16B-aligned chunks)
    char* p = (char*)d_ws;
    const size_t need = 63062016ull;
    if (ws_size < need) return;

    float*          badd   = (float*)p;          p += 16384;     // [4096]
    unsigned short* h_bf   = (unsigned short*)p; p += 1048576;   // [512][1024]
    unsigned short* wq_bf  = (unsigned short*)p; p += 2097152;   // [1024][1024]
    unsigned short* wkT_bf = (unsigned short*)p; p += 2097152;   // [2][1024][512]
    unsigned short* wv_bf  = (unsigned short*)p; p += 2097152;   // [1024][1024]
    unsigned short* wo_bf  = (unsigned short*)p; p += 2097152;   // [1024][1024]
    unsigned short* q_bf   = (unsigned short*)p; p += 1048576;   // [512][1024]
    unsigned short* sac_bf = (unsigned short*)p; p += 2097152;   // [512][2048]
    unsigned short* ctx_bf = (unsigned short*)p; p += 1048576;   // [512][1024]
    unsigned short* acat   = (unsigned short*)p; p += 3145728;   // [512][3072]
    unsigned short* wcat   = (unsigned short*)p; p += 25165824;  // [4096][3072]
    // overlay region: {qtl, spart, mlpart} (attention) / {gates} (after combine)
    char* ov = p;
    float*          qtl      = (float*)ov;                       // [512][2][1024] f32
    unsigned short* spart_bf = (unsigned short*)(ov + 4194304);  // [512][8][2][1024] bf16
    float*          mlpart   = (float*)(ov + 4194304 + 16777216);// [512][8][2][2]
    float*          gates    = (float*)ov;                       // [512][4096] (aliases, later)

    const float* wk_f = in_w + (long)kD * kD;
    const float* bq = in_b;
    const float* bv = in_b + 2 * kD;

    auto cvt = [&](const float* src, unsigned short* dst, int rows, int scols,
                   int dcols, int coloff) {
        int n8 = rows * (scols / 8);
        cvt_bf16<<<(n8 + 255) / 256, 256, 0, stream>>>(src, dst, scols / 8, dcols, coloff, n8);
    };

    // ---- conversions (round-3 proven forms)
    badd_kernel<<<16, 256, 0, stream>>>(b_ih, b_hh, badd);
    cvt(h, h_bf, 512, 1024, 1024, 0);
    cvt(in_w, wq_bf, 1024, 1024, 1024, 0);
    tcvt_wk<<<dim3(32, 16, 2), 256, 0, stream>>>(wk_f, wkT_bf);
    cvt(in_w + 2L * kD * kD, wv_bf, 1024, 1024, 1024, 0);
    cvt(wo, wo_bf, 1024, 1024, 1024, 0);
    cvt(w_ih, wcat, 4096, 2048, 3072, 0);
    cvt(w_hh, wcat, 4096, 1024, 3072, 2048);

    // 1. q_bf = bf16(h @ wq^T + bq)   (q.b_k dropped: softmax-shift-invariant)
    gemm_bf16<<<dim3(8, 8, 1), 256, 0, stream>>>(
        h_bf, 1024, 0, wq_bf, 1024, 0,
        nullptr, 0, 0, q_bf, 1024, 0, bq, 0, 1024);

    // 2. qtl[:, z, :] = q_z @ wkT_z^T   (f32 out; scale pre-folded in wkT)
    gemm_bf16<<<dim3(8, 8, 2), 256, 0, stream>>>(
        q_bf, 1024, 512, wkT_bf, 512, 524288,
        qtl, 2048, 1024, nullptr, 0, 0, nullptr, 0, 512);

    // 3. barrier-free streaming attention (coalesced loads) -> partials
    attn7<<<kB, 512, 0, stream>>>(xall, qtl, spart_bf, mlpart);

    // 4. combine 8 partials -> sac_bf (bf16)
    attn_combine8<<<kB, 256, 0, stream>>>(spart_bf, mlpart, sac_bf);

    // 5. ctx_bf[:, z*512:] = bf16(s_z @ wv_z^T + bv_z)
    gemm_bf16<<<dim3(4, 8, 2), 256, 0, stream>>>(
        sac_bf, 2048, 1024, wv_bf, 1024, 524288,
        nullptr, 0, 0, ctx_bf, 1024, 512, bv, 512, 1024);

    // 6. acat[:, 0:1024] = bf16(ctx @ wo^T + bo)
    gemm_bf16<<<dim3(8, 8, 1), 256, 0, stream>>>(
        ctx_bf, 1024, 0, wo_bf, 1024, 0,
        nullptr, 0, 0, acat, 3072, 0, bo, 0, 1024);

    // remaining acat columns
    cvt(ext, acat, 512, 1024, 3072, 1024);
    cvt(h,   acat, 512, 1024, 3072, 2048);

    // 7. gates = acat @ wcat^T + (b_ih + b_hh)   (f32 out; aliases attn scratch)
    gemm_bf16<<<dim3(32, 8, 1), 256, 0, stream>>>(
        acat, 3072, 0, wcat, 3072, 0,
        gates, 4096, 0, nullptr, 0, 0, badd, 0, 3072);

    // 8. LSTM cell + LayerNorm
    lstm_ln<<<kB, 256, 0, stream>>>(gates, c, ln_w, ln_b, out0, out1);
}

// Round 8
// 408.997 us; speedup vs baseline: 2.6982x; 1.0879x over previous
//
#include <hip/hip_runtime.h>
#include <math.h>
#include <stdint.h>

constexpr int kD  = 1024;   // model dim
constexpr int kB  = 512;    // batch
constexpr int kN  = 512;    // states per batch
constexpr int kDH = 512;    // head dim (H=2)

using bf16x8 = __attribute__((ext_vector_type(8))) short;
using f32x4v = __attribute__((ext_vector_type(4))) float;
using us8    = __attribute__((ext_vector_type(8))) unsigned short;
using us4    = __attribute__((ext_vector_type(4))) unsigned short;

__device__ __forceinline__ unsigned short f2bf(float f) {
    uint32_t u = __float_as_uint(f);
    u += 0x7fffu + ((u >> 16) & 1u);     // round-to-nearest-even
    return (unsigned short)(u >> 16);
}

__device__ __forceinline__ float bf2f(unsigned short s) {
    return __uint_as_float((uint32_t)s << 16);
}

__device__ __forceinline__ void async16(const void* g, void* l) {
    __builtin_amdgcn_global_load_lds(
        (const __attribute__((address_space(1))) uint32_t*)g,
        (__attribute__((address_space(3))) uint32_t*)l, 16, 0, 0);
}

// ---------------------------------------------------------------------------
// f32 -> bf16 convert with optional column restride/offset. (proven)
// ---------------------------------------------------------------------------
__global__ __launch_bounds__(256)
void cvt_bf16(const float* __restrict__ src, unsigned short* __restrict__ dst,
              int scols8, int dcols, int coloff, int n8)
{
    int idx = blockIdx.x * 256 + threadIdx.x;
    if (idx >= n8) return;
    int row = idx / scols8;
    int c = (idx - row * scols8) * 8;
    const float4* s = (const float4*)(src + (long)row * ((long)scols8 * 8) + c);
    float4 v0 = s[0], v1 = s[1];
    us8 o;
    o[0] = f2bf(v0.x); o[1] = f2bf(v0.y); o[2] = f2bf(v0.z); o[3] = f2bf(v0.w);
    o[4] = f2bf(v1.x); o[5] = f2bf(v1.y); o[6] = f2bf(v1.z); o[7] = f2bf(v1.w);
    *(us8*)(dst + (long)row * dcols + coloff + c) = o;
}

// ---------------------------------------------------------------------------
// wk transpose+convert with SCALE FOLDED IN (proven).
// ---------------------------------------------------------------------------
__global__ __launch_bounds__(256)
void tcvt_wk(const float* __restrict__ wk, unsigned short* __restrict__ dst)
{
    __shared__ float t[32][33];
    const int nt = blockIdx.x;     // 0..31 (n tiles)
    const int kt = blockIdx.y;     // 0..15 (k tiles)
    const int hh = blockIdx.z;     // head
    const int tx = threadIdx.x & 31, ty = threadIdx.x >> 5;   // 32 x 8
    const float scale = 0.044194173824159216f;   // 1/sqrt(512)
#pragma unroll
    for (int j = 0; j < 4; ++j)
        t[ty + j * 8][tx] = wk[(long)(hh * 512 + kt * 32 + ty + j * 8) * kD + nt * 32 + tx];
    __syncthreads();
#pragma unroll
    for (int j = 0; j < 4; ++j) {
        int n = nt * 32 + ty + j * 8;
        int k = kt * 32 + tx;
        dst[(long)hh * 524288 + (long)n * 512 + k] = f2bf(t[tx][ty + j * 8] * scale);
    }
}

// ---------------------------------------------------------------------------
// gemm64: bf16 MFMA GEMM, NT, 64x64 tile, BK=32, 256 threads (4 waves 2x2).
// Small-M/N shapes: 2-4x more blocks than the 64x128 kernel -> fills the chip.
// ---------------------------------------------------------------------------
__global__ __launch_bounds__(256)
void gemm64(const unsigned short* __restrict__ A, int lda, long sAz,
            const unsigned short* __restrict__ B, int ldb, long sBz,
            float* __restrict__ Cf, int ldcf, long sCfz,
            unsigned short* __restrict__ Cb, int ldcb, long sCbz,
            const float* __restrict__ bias, long sbz, int K)
{
    __shared__ short As[4][64][8];
    __shared__ short Bs[4][64][8];
    A += (long)blockIdx.z * sAz;
    B += (long)blockIdx.z * sBz;

    const int tid = threadIdx.x;
    const int l = tid & 63, w = tid >> 6;
    const int wr = w >> 1, wc = w & 1;
    const int bm = blockIdx.y * 64, bn = blockIdx.x * 64;

    f32x4v acc[2][2] = {};

    for (int k0 = 0; k0 < K; k0 += 32) {
        __syncthreads();
        {
            int ks = tid >> 6, r = tid & 63;
            async16(A + (long)(bm + r) * lda + k0 + ks * 8, (short*)As + (long)tid * 8);
            async16(B + (long)(bn + r) * ldb + k0 + ks * 8, (short*)Bs + (long)tid * 8);
        }
        __syncthreads();   // vmcnt drained before barrier (m97 pattern)

        const int ks = l >> 4, rr = l & 15;
        bf16x8 a[2], b[2];
#pragma unroll
        for (int t = 0; t < 2; ++t) {
            a[t] = *(const bf16x8*)&As[ks][wr * 32 + t * 16 + rr][0];
            b[t] = *(const bf16x8*)&Bs[ks][wc * 32 + t * 16 + rr][0];
        }
#pragma unroll
        for (int mt = 0; mt < 2; ++mt)
#pragma unroll
            for (int nt = 0; nt < 2; ++nt)
                acc[mt][nt] = __builtin_amdgcn_mfma_f32_16x16x32_bf16(
                    a[mt], b[nt], acc[mt][nt], 0, 0, 0);
    }

    const int rr = l & 15, rg = l >> 4;
#pragma unroll
    for (int mt = 0; mt < 2; ++mt) {
#pragma unroll
        for (int nt = 0; nt < 2; ++nt) {
            const int n = bn + wc * 32 + nt * 16 + rr;
            float bb = bias ? bias[(long)blockIdx.z * sbz + n] : 0.f;
#pragma unroll
            for (int r = 0; r < 4; ++r) {
                const int m = bm + wr * 32 + mt * 16 + rg * 4 + r;
                float val = acc[mt][nt][r] + bb;
                if (Cf) Cf[(long)blockIdx.z * sCfz + (long)m * ldcf + n] = val;
                if (Cb) Cb[(long)blockIdx.z * sCbz + (long)m * ldcb + n] = f2bf(val);
            }
        }
    }
}

// ---------------------------------------------------------------------------
// gemm_gates: 64x128 tile, BK=64 (24 K-steps instead of 48 -> half the
// barrier drains), dual-bias epilogue (b_ih + b_hh in-kernel).
// ---------------------------------------------------------------------------
__global__ __launch_bounds__(256)
void gemm_gates(const unsigned short* __restrict__ A, int lda,
                const unsigned short* __restrict__ B, int ldb,
                float* __restrict__ Cf, int ldcf,
                const float* __restrict__ b1, const float* __restrict__ b2,
                int K)
{
    __shared__ short As[8][64][8];
    __shared__ short Bs[8][128][8];

    const int tid = threadIdx.x;
    const int l = tid & 63, w = tid >> 6;
    const int wr = w >> 1, wc = w & 1;
    const int bm = blockIdx.y * 64, bn = blockIdx.x * 128;

    f32x4v acc[2][4] = {};

    for (int k0 = 0; k0 < K; k0 += 64) {
        __syncthreads();
#pragma unroll
        for (int j = 0; j < 2; ++j) {
            int ca = j * 256 + tid;            // 0..511: ks 0..7, row 0..63
            int ks = ca >> 6, r = ca & 63;
            async16(A + (long)(bm + r) * lda + k0 + ks * 8, (short*)As + (long)ca * 8);
        }
#pragma unroll
        for (int j = 0; j < 4; ++j) {
            int ca = j * 256 + tid;            // 0..1023: ks 0..7, row 0..127
            int ks = ca >> 7, r = ca & 127;
            async16(B + (long)(bn + r) * ldb + k0 + ks * 8, (short*)Bs + (long)ca * 8);
        }
        __syncthreads();

        const int ksl = l >> 4, rr = l & 15;
#pragma unroll
        for (int p = 0; p < 2; ++p) {
            bf16x8 a[2], b[4];
#pragma unroll
            for (int t = 0; t < 2; ++t)
                a[t] = *(const bf16x8*)&As[p * 4 + ksl][wr * 32 + t * 16 + rr][0];
#pragma unroll
            for (int t = 0; t < 4; ++t)
                b[t] = *(const bf16x8*)&Bs[p * 4 + ksl][wc * 64 + t * 16 + rr][0];
#pragma unroll
            for (int mt = 0; mt < 2; ++mt)
#pragma unroll
                for (int nt = 0; nt < 4; ++nt)
                    acc[mt][nt] = __builtin_amdgcn_mfma_f32_16x16x32_bf16(
                        a[mt], b[nt], acc[mt][nt], 0, 0, 0);
        }
    }

    const int rr = l & 15, rg = l >> 4;
#pragma unroll
    for (int mt = 0; mt < 2; ++mt) {
#pragma unroll
        for (int nt = 0; nt < 4; ++nt) {
            const int n = bn + wc * 64 + nt * 16 + rr;
            const float bb = b1[n] + b2[n];
#pragma unroll
            for (int r = 0; r < 4; ++r) {
                const int m = bm + wr * 32 + mt * 16 + rg * 4 + r;
                Cf[(long)m * ldcf + n] = acc[mt][nt][r] + bb;
            }
        }
    }
}

// ---------------------------------------------------------------------------
// attn7 (round-7 proven, UNCHANGED): barrier-free streaming attention.
// ---------------------------------------------------------------------------
__global__ __launch_bounds__(512, 4)
void attn7(const float* __restrict__ xall,        // [B][N][D] f32
           const float* __restrict__ qt,          // [B][2][D] f32 (pre-scaled)
           unsigned short* __restrict__ spart_bf, // [B][8][2][1024] bf16
           float* __restrict__ mlpart)            // [B][8][2][2] f32
{
    const int b = blockIdx.x;
    const int tid = threadIdx.x;
    const int w = tid >> 6, l = tid & 63;

    float qa[16], qb[16];
    {
        const float* qp = qt + (long)b * 2048 + l * 4;
#pragma unroll
        for (int q = 0; q < 4; ++q) {
            float4 v0 = *(const float4*)(qp + q * 256);
            float4 v1 = *(const float4*)(qp + 1024 + q * 256);
            qa[q*4+0] = v0.x; qa[q*4+1] = v0.y; qa[q*4+2] = v0.z; qa[q*4+3] = v0.w;
            qb[q*4+0] = v1.x; qb[q*4+1] = v1.y; qb[q*4+2] = v1.z; qb[q*4+3] = v1.w;
        }
    }

    float m0 = -1e30f, l0 = 0.f, m1 = -1e30f, l1 = 0.f;
    float sa[16] = {}, sb[16] = {};

    const float* xr = xall + ((long)b * kN + w * 64) * kD + l * 4;

    for (int r = 0; r < 64; ++r) {
        float xv[16];
#pragma unroll
        for (int q = 0; q < 4; ++q) {
            float4 v = *(const float4*)(xr + q * 256);
            xv[q*4+0] = v.x; xv[q*4+1] = v.y; xv[q*4+2] = v.z; xv[q*4+3] = v.w;
        }
        xr += kD;

        float c0=0.f,c1=0.f,c2=0.f,c3=0.f, e0=0.f,e1=0.f,e2=0.f,e3=0.f;
#pragma unroll
        for (int q = 0; q < 4; ++q) {
            c0 += xv[q*4+0]*qa[q*4+0]; c1 += xv[q*4+1]*qa[q*4+1];
            c2 += xv[q*4+2]*qa[q*4+2]; c3 += xv[q*4+3]*qa[q*4+3];
            e0 += xv[q*4+0]*qb[q*4+0]; e1 += xv[q*4+1]*qb[q*4+1];
            e2 += xv[q*4+2]*qb[q*4+2]; e3 += xv[q*4+3]*qb[q*4+3];
        }
        float d0 = (c0 + c1) + (c2 + c3);
        float d1 = (e0 + e1) + (e2 + e3);
#pragma unroll
        for (int mm = 32; mm >= 1; mm >>= 1) {
            d0 += __shfl_xor(d0, mm);
            d1 += __shfl_xor(d1, mm);
        }

        if (d0 > m0 + 8.f) {                       // defer-max (T13), uniform
            float rsc = __expf(m0 - d0);
            l0 *= rsc;
#pragma unroll
            for (int j = 0; j < 16; ++j) sa[j] *= rsc;
            m0 = d0;
        }
        float p0 = __expf(d0 - m0);
        l0 += p0;

        if (d1 > m1 + 8.f) {
            float rsc = __expf(m1 - d1);
            l1 *= rsc;
#pragma unroll
            for (int j = 0; j < 16; ++j) sb[j] *= rsc;
            m1 = d1;
        }
        float p1 = __expf(d1 - m1);
        l1 += p1;

#pragma unroll
        for (int j = 0; j < 16; ++j) {
            sa[j] += p0 * xv[j];
            sb[j] += p1 * xv[j];
        }
    }

    unsigned short* sp0 = spart_bf + (((long)b * 8 + w) * 2 + 0) * 1024 + l * 4;
    unsigned short* sp1 = spart_bf + (((long)b * 8 + w) * 2 + 1) * 1024 + l * 4;
#pragma unroll
    for (int q = 0; q < 4; ++q) {
        us4 o0, o1;
        o0[0] = f2bf(sa[q*4+0]); o0[1] = f2bf(sa[q*4+1]);
        o0[2] = f2bf(sa[q*4+2]); o0[3] = f2bf(sa[q*4+3]);
        o1[0] = f2bf(sb[q*4+0]); o1[1] = f2bf(sb[q*4+1]);
        o1[2] = f2bf(sb[q*4+2]); o1[3] = f2bf(sb[q*4+3]);
        *(us4*)(sp0 + q * 256) = o0;
        *(us4*)(sp1 + q * 256) = o1;
    }

    if (l == 0) {
        float* mlp = mlpart + (((long)b * 8 + w) * 2) * 2;
        mlp[0] = m0; mlp[1] = l0; mlp[2] = m1; mlp[3] = l1;
    }
}

// ---------------------------------------------------------------------------
// Combine 8 per-wave partials -> normalized sums (proven).
// ---------------------------------------------------------------------------
__global__ __launch_bounds__(256)
void attn_combine8(const unsigned short* __restrict__ spart_bf,
                   const float* __restrict__ mlpart,
                   unsigned short* __restrict__ sac_bf)
{
    const int b = blockIdx.x;
    const int tid = threadIdx.x;
    const int h = tid >> 7, d0 = (tid & 127) * 8;

    float m[8], lv[8];
#pragma unroll
    for (int c = 0; c < 8; ++c) {
        const float* mlp = mlpart + (((long)b * 8 + c) * 2 + h) * 2;
        m[c] = mlp[0]; lv[c] = mlp[1];
    }
    float ms = m[0];
#pragma unroll
    for (int c = 1; c < 8; ++c) ms = fmaxf(ms, m[c]);
    float wgt[8], L = 0.f;
#pragma unroll
    for (int c = 0; c < 8; ++c) { wgt[c] = __expf(m[c] - ms); L += wgt[c] * lv[c]; }
    const float inv = 1.0f / L;

    float acc[8] = {};
#pragma unroll
    for (int c = 0; c < 8; ++c) {
        us8 sv = *(const us8*)(spart_bf + (((long)b * 8 + c) * 2 + h) * 1024 + d0);
#pragma unroll
        for (int j = 0; j < 8; ++j)
            acc[j] += wgt[c] * bf2f(sv[j]);
    }
    us8 o;
#pragma unroll
    for (int j = 0; j < 8; ++j) o[j] = f2bf(acc[j] * inv);
    *(us8*)(sac_bf + (long)b * 2048 + h * kD + d0) = o;
}

// ---------------------------------------------------------------------------
// Fused LSTM cell + LayerNorm (proven).
// ---------------------------------------------------------------------------
__device__ __forceinline__ float sigm(float x) { return 1.0f / (1.0f + __expf(-x)); }

__global__ __launch_bounds__(256)
void lstm_ln(const float* __restrict__ gates, const float* __restrict__ cin,
             const float* __restrict__ ln_w, const float* __restrict__ ln_b,
             float* __restrict__ out0, float* __restrict__ out1)
{
    __shared__ float red[2][4];
    __shared__ float stats[2];

    const int b = blockIdx.x;
    const int tid = threadIdx.x;
    const int d4 = tid * 4;
    const float* g = gates + (long)b * 4096;

    float4 gi = *(const float4*)(g + d4);
    float4 gf = *(const float4*)(g + 1024 + d4);
    float4 gg = *(const float4*)(g + 2048 + d4);
    float4 go = *(const float4*)(g + 3072 + d4);
    float4 cv = *(const float4*)(cin + (long)b * kD + d4);

    float iv[4] = {gi.x, gi.y, gi.z, gi.w};
    float fv[4] = {gf.x, gf.y, gf.z, gf.w};
    float gv[4] = {gg.x, gg.y, gg.z, gg.w};
    float ov[4] = {go.x, go.y, go.z, go.w};
    float cc[4] = {cv.x, cv.y, cv.z, cv.w};

    float nc[4], nh[4];
#pragma unroll
    for (int u = 0; u < 4; ++u) {
        nc[u] = sigm(fv[u]) * cc[u] + sigm(iv[u]) * tanhf(gv[u]);
        nh[u] = sigm(ov[u]) * tanhf(nc[u]);
    }
    *(float4*)(out1 + (long)b * kD + d4) = make_float4(nc[0], nc[1], nc[2], nc[3]);

    float sum = nh[0] + nh[1] + nh[2] + nh[3];
    float ss  = nh[0]*nh[0] + nh[1]*nh[1] + nh[2]*nh[2] + nh[3]*nh[3];
#pragma unroll
    for (int m = 32; m >= 1; m >>= 1) {
        sum += __shfl_xor(sum, m);
        ss  += __shfl_xor(ss, m);
    }
    const int wave = tid >> 6, lane = tid & 63;
    if (lane == 0) { red[0][wave] = sum; red[1][wave] = ss; }
    __syncthreads();
    if (tid == 0) {
        float s = red[0][0] + red[0][1] + red[0][2] + red[0][3];
        float q = red[1][0] + red[1][1] + red[1][2] + red[1][3];
        float mu = s / (float)kD;
        float var = q / (float)kD - mu * mu;
        stats[0] = mu;
        stats[1] = rsqrtf(var + 1e-5f);
    }
    __syncthreads();
    const float mu = stats[0], rstd = stats[1];
    float4 lw = *(const float4*)(ln_w + d4);
    float4 lb = *(const float4*)(ln_b + d4);
    float lwv[4] = {lw.x, lw.y, lw.z, lw.w};
    float lbv[4] = {lb.x, lb.y, lb.z, lb.w};
    float o[4];
#pragma unroll
    for (int u = 0; u < 4; ++u)
        o[u] = (nh[u] - mu) * rstd * lwv[u] + lbv[u];
    *(float4*)(out0 + (long)b * kD + d4) = make_float4(o[0], o[1], o[2], o[3]);
}

// ---------------------------------------------------------------------------
extern "C" void kernel_launch(void* const* d_in, const int* in_sizes, int n_in,
                              void* d_out, int out_size, void* d_ws, size_t ws_size,
                              hipStream_t stream)
{
    (void)in_sizes; (void)n_in; (void)out_size;

    const float* h    = (const float*)d_in[0];
    const float* c    = (const float*)d_in[1];
    const float* xall = (const float*)d_in[2];
    const float* ext  = (const float*)d_in[3];
    const float* in_w = (const float*)d_in[4];
    const float* in_b = (const float*)d_in[5];
    const float* wo   = (const float*)d_in[6];
    const float* bo   = (const float*)d_in[7];
    const float* w_ih = (const float*)d_in[8];
    const float* b_ih = (const float*)d_in[9];
    const float* w_hh = (const float*)d_in[10];
    const float* b_hh = (const float*)d_in[11];
    const float* ln_w = (const float*)d_in[12];
    const float* ln_b = (const float*)d_in[13];

    float* out0 = (float*)d_out;              // LN(new_h) [512x1024]
    float* out1 = out0 + (long)kB * kD;       // new_c     [512x1024]

    // ---- workspace layout (identical offsets to round 7; badd slot unused)
    char* p = (char*)d_ws;
    const size_t need = 63062016ull;
    if (ws_size < need) return;

    p += 16384;                                                  // (was badd)
    unsigned short* h_bf   = (unsigned short*)p; p += 1048576;   // [512][1024]
    unsigned short* wq_bf  = (unsigned short*)p; p += 2097152;   // [1024][1024]
    unsigned short* wkT_bf = (unsigned short*)p; p += 2097152;   // [2][1024][512]
    unsigned short* wv_bf  = (unsigned short*)p; p += 2097152;   // [1024][1024]
    unsigned short* wo_bf  = (unsigned short*)p; p += 2097152;   // [1024][1024]
    unsigned short* q_bf   = (unsigned short*)p; p += 1048576;   // [512][1024]
    unsigned short* sac_bf = (unsigned short*)p; p += 2097152;   // [512][2048]
    unsigned short* ctx_bf = (unsigned short*)p; p += 1048576;   // [512][1024]
    unsigned short* acat   = (unsigned short*)p; p += 3145728;   // [512][3072]
    unsigned short* wcat   = (unsigned short*)p; p += 25165824;  // [4096][3072]
    // overlay region: {qtl, spart, mlpart} (attention) / {gates} (after combine)
    char* ov = p;
    float*          qtl      = (float*)ov;                       // [512][2][1024] f32
    unsigned short* spart_bf = (unsigned short*)(ov + 4194304);  // [512][8][2][1024] bf16
    float*          mlpart   = (float*)(ov + 4194304 + 16777216);// [512][8][2][2]
    float*          gates    = (float*)ov;                       // [512][4096] (aliases, later)

    const float* wk_f = in_w + (long)kD * kD;
    const float* bq = in_b;
    const float* bv = in_b + 2 * kD;

    auto cvt = [&](const float* src, unsigned short* dst, int rows, int scols,
                   int dcols, int coloff) {
        int n8 = rows * (scols / 8);
        cvt_bf16<<<(n8 + 255) / 256, 256, 0, stream>>>(src, dst, scols / 8, dcols, coloff, n8);
    };

    // ---- conversions (proven forms)
    cvt(h, h_bf, 512, 1024, 1024, 0);
    cvt(in_w, wq_bf, 1024, 1024, 1024, 0);
    tcvt_wk<<<dim3(32, 16, 2), 256, 0, stream>>>(wk_f, wkT_bf);
    cvt(in_w + 2L * kD * kD, wv_bf, 1024, 1024, 1024, 0);
    cvt(wo, wo_bf, 1024, 1024, 1024, 0);
    cvt(w_ih, wcat, 4096, 2048, 3072, 0);
    cvt(w_hh, wcat, 4096, 1024, 3072, 2048);

    // 1. q_bf = bf16(h @ wq^T + bq)
    gemm64<<<dim3(16, 8, 1), 256, 0, stream>>>(
        h_bf, 1024, 0, wq_bf, 1024, 0,
        nullptr, 0, 0, q_bf, 1024, 0, bq, 0, 1024);

    // 2. qtl[:, z, :] = q_z @ wkT_z^T   (f32 out; scale pre-folded in wkT)
    gemm64<<<dim3(16, 8, 2), 256, 0, stream>>>(
        q_bf, 1024, 512, wkT_bf, 512, 524288,
        qtl, 2048, 1024, nullptr, 0, 0, nullptr, 0, 512);

    // 3. barrier-free streaming attention -> partials (UNCHANGED)
    attn7<<<kB, 512, 0, stream>>>(xall, qtl, spart_bf, mlpart);

    // 4. combine 8 partials -> sac_bf (bf16)
    attn_combine8<<<kB, 256, 0, stream>>>(spart_bf, mlpart, sac_bf);

    // 5. ctx_bf[:, z*512:] = bf16(s_z @ wv_z^T + bv_z)
    gemm64<<<dim3(8, 8, 2), 256, 0, stream>>>(
        sac_bf, 2048, 1024, wv_bf, 1024, 524288,
        nullptr, 0, 0, ctx_bf, 1024, 512, bv, 512, 1024);

    // 6. acat[:, 0:1024] = bf16(ctx @ wo^T + bo)
    gemm64<<<dim3(16, 8, 1), 256, 0, stream>>>(
        ctx_bf, 1024, 0, wo_bf, 1024, 0,
        nullptr, 0, 0, acat, 3072, 0, bo, 0, 1024);

    // remaining acat columns
    cvt(ext, acat, 512, 1024, 3072, 1024);
    cvt(h,   acat, 512, 1024, 3072, 2048);

    // 7. gates = acat @ wcat^T + b_ih + b_hh   (BK=64, dual-bias epilogue)
    gemm_gates<<<dim3(32, 8), 256, 0, stream>>>(
        acat, 3072, wcat, 3072, gates, 4096, b_ih, b_hh, 3072);

    // 8. LSTM cell + LayerNorm
    lstm_ln<<<kB, 256, 0, stream>>>(gates, c, ln_w, ln_b, out0, out1);
}